// Round 1
// baseline (1759.709 us; speedup 1.0000x reference)
//
#include <hip/hip_runtime.h>
#include <math.h>

#define NN 20000
#define CC 256
#define HH 8
#define EE 160000
#define TE 320000

__device__ __forceinline__ float gelu_exact(float x){
    return 0.5f*x*(1.0f+erff(x*0.7071067811865476f));
}

// ======================= CSR build (once per call) =======================
__global__ void hist_k(const int* __restrict__ ei0, const int* __restrict__ ei1,
                       int* __restrict__ cnt){
    int e = blockIdx.x*256 + threadIdx.x;
    if (e < TE){
        int dst = (e < EE) ? ei0[EE + e] : ei1[EE + (e - EE)];
        atomicAdd(&cnt[dst], 1);
    }
}

__global__ void scan_block_k(const int* __restrict__ cnt, int* __restrict__ incl,
                             int* __restrict__ bsum){
    __shared__ int tmp[256];
    int tid = threadIdx.x;
    int i = blockIdx.x*256 + tid;
    int v = (i < NN) ? cnt[i] : 0;
    tmp[tid] = v;
    __syncthreads();
    for (int d=1; d<256; d<<=1){
        int t = (tid>=d) ? tmp[tid-d] : 0;
        __syncthreads();
        tmp[tid] += t;
        __syncthreads();
    }
    if (i < NN) incl[i] = tmp[tid];
    if (tid == 255) bsum[blockIdx.x] = tmp[255];
}

__global__ void scan_bsum_k(int* bsum, int nb){
    if (threadIdx.x==0 && blockIdx.x==0){
        int acc = 0;
        for (int i=0;i<nb;++i){ int t=bsum[i]; bsum[i]=acc; acc+=t; }
    }
}

__global__ void finalize_rowptr_k(const int* __restrict__ cnt, const int* __restrict__ incl,
                                  const int* __restrict__ bsum, int* __restrict__ row_ptr){
    int i = blockIdx.x*256 + threadIdx.x;
    if (i < NN) row_ptr[i] = incl[i] - cnt[i] + bsum[blockIdx.x];
    if (i == NN) row_ptr[NN] = TE;
}

__global__ void scatter_k(const int* __restrict__ ei0, const int* __restrict__ ei1,
                          const int* __restrict__ row_ptr, int* __restrict__ cursor,
                          int* __restrict__ eids, int* __restrict__ esrc){
    int e = blockIdx.x*256 + threadIdx.x;
    if (e < TE){
        int src, dst;
        if (e < EE){ src = ei0[e]; dst = ei0[EE+e]; }
        else { int ee=e-EE; src = ei1[ee]; dst = ei1[EE+ee]; }
        esrc[e] = src;
        int pos = atomicAdd(&cursor[dst], 1);
        eids[row_ptr[dst] + pos] = e;
    }
}

// ======================= K1: kqv GEMM (fp32, 128x128 tile) =======================
// C[20000,768] = A[20000,256] @ B[256,768] + bias, written to split k/q/v buffers
__global__ __launch_bounds__(256,2) void gemm_kqv_k(const float* __restrict__ A,
        const float* __restrict__ Bw, const float* __restrict__ bias,
        float* __restrict__ kb, float* __restrict__ qb, float* __restrict__ vb){
    __shared__ float As[16][132];   // [kk][row]
    __shared__ float Bs[16][132];   // [kk][col]
    int tid = threadIdx.x;
    int row0 = blockIdx.x*128, col0 = blockIdx.y*128;
    int tx = tid & 15, ty = tid >> 4;
    float acc[8][8];
    #pragma unroll
    for (int i=0;i<8;++i)
        #pragma unroll
        for (int j=0;j<8;++j) acc[i][j]=0.f;

    for (int k0=0; k0<256; k0+=16){
        int t = tid;
        #pragma unroll
        for (int it=0; it<2; ++it, t+=256){
            int r = t >> 2;             // 0..127
            int kc = (t & 3) << 2;      // 0,4,8,12
            float4 v = {0.f,0.f,0.f,0.f};
            int grow = row0 + r;
            if (grow < NN) v = *(const float4*)&A[(size_t)grow*256 + k0 + kc];
            As[kc+0][r]=v.x; As[kc+1][r]=v.y; As[kc+2][r]=v.z; As[kc+3][r]=v.w;
        }
        t = tid;
        #pragma unroll
        for (int it=0; it<2; ++it, t+=256){
            int kk = t >> 5;            // 0..15
            int c = (t & 31) << 2;      // 0..124
            *(float4*)&Bs[kk][c] = *(const float4*)&Bw[(size_t)(k0+kk)*768 + col0 + c];
        }
        __syncthreads();
        #pragma unroll
        for (int kk=0; kk<16; ++kk){
            float a[8], b[8];
            *(float4*)&a[0] = *(const float4*)&As[kk][ty*8];
            *(float4*)&a[4] = *(const float4*)&As[kk][ty*8+4];
            *(float4*)&b[0] = *(const float4*)&Bs[kk][tx*8];
            *(float4*)&b[4] = *(const float4*)&Bs[kk][tx*8+4];
            #pragma unroll
            for (int i=0;i<8;++i)
                #pragma unroll
                for (int j=0;j<8;++j) acc[i][j] += a[i]*b[j];
        }
        __syncthreads();
    }
    // epilogue: split into k/q/v
    int colbase = col0 + tx*8;
    float* obuf; int cm;
    if (colbase < 256){ obuf = kb; cm = colbase; }
    else if (colbase < 512){ obuf = qb; cm = colbase - 256; }
    else { obuf = vb; cm = colbase - 512; }
    #pragma unroll
    for (int i=0;i<8;++i){
        int grow = row0 + ty*8 + i;
        if (grow >= NN) continue;
        float o[8];
        #pragma unroll
        for (int j=0;j<8;++j) o[j] = acc[i][j] + bias[colbase + j];
        *(float4*)&obuf[(size_t)grow*256 + cm]     = *(float4*)&o[0];
        *(float4*)&obuf[(size_t)grow*256 + cm + 4] = *(float4*)&o[4];
    }
}

// ======================= K2: per-node relation transforms =======================
// out[n, h*32+f] = sum_d in[n, h*32+d] * W[h][d][f]     (node-side, 8x cheaper than edge-side)
__global__ __launch_bounds__(256) void rel_transform_k(const float* __restrict__ kbuf,
        const float* __restrict__ vbuf, const float* __restrict__ krel_l,
        const float* __restrict__ vrel_l, float* __restrict__ kr0, float* __restrict__ kr1,
        float* __restrict__ vr0, float* __restrict__ vr1){
    __shared__ float Wl[1024];
    __shared__ float xin[256];
    int tid = threadIdx.x;
    int h = blockIdx.y;
    int z = blockIdx.z;               // 0:kr0 1:kr1 2:vr0 3:vr1
    int r = z & 1, isv = z >> 1;
    const float* in = isv ? vbuf : kbuf;
    const float* Wm = (isv ? vrel_l : krel_l) + r*8192 + h*1024;
    float* outp = (z==0)?kr0:((z==1)?kr1:((z==2)?vr0:vr1));
    *(float4*)&Wl[tid*4] = *(const float4*)&Wm[tid*4];
    int nl = tid >> 5, f = tid & 31;
    int node = blockIdx.x*8 + nl;
    xin[tid] = in[(size_t)node*256 + h*32 + f];
    __syncthreads();
    float acc = 0.f;
    #pragma unroll
    for (int d=0; d<32; ++d)
        acc += xin[nl*32 + d] * Wl[d*32 + f];
    outp[(size_t)node*256 + h*32 + f] = acc;
}

// ======================= K3: edge logits (one wave per edge) =======================
__global__ __launch_bounds__(256) void edge_logits_k(const float* __restrict__ q,
        const float* __restrict__ kr0, const float* __restrict__ kr1,
        const int* __restrict__ ei0, const int* __restrict__ ei1,
        const float* __restrict__ prel_l, float* __restrict__ logits){
    int lane = threadIdx.x & 63;
    int e = blockIdx.x*4 + (threadIdx.x >> 6);   // grid covers TE exactly
    int src, dst, r; const float* kr;
    if (e < EE){ src = ei0[e]; dst = ei0[EE+e]; kr = kr0; r = 0; }
    else { int ee = e-EE; src = ei1[ee]; dst = ei1[EE+ee]; kr = kr1; r = 1; }
    float4 qv = *(const float4*)&q[(size_t)dst*256 + lane*4];
    float4 kv = *(const float4*)&kr[(size_t)src*256 + lane*4];
    float p = qv.x*kv.x + qv.y*kv.y + qv.z*kv.z + qv.w*kv.w;
    p += __shfl_xor(p, 1);
    p += __shfl_xor(p, 2);
    p += __shfl_xor(p, 4);
    if ((lane & 7) == 0){
        int h = lane >> 3;
        logits[(size_t)e*8 + h] = p * prel_l[r*8 + h] * 0.17677669529663687f; // /sqrt(32)
    }
}

// ======================= K4: per-node softmax + aggregate (one wave per node) ===========
__global__ __launch_bounds__(256) void node_agg_k(float* __restrict__ logits,
        const float* __restrict__ vr0, const float* __restrict__ vr1,
        const int* __restrict__ row_ptr, const int* __restrict__ eids,
        const int* __restrict__ esrc, float* __restrict__ agg){
    int wave = threadIdx.x >> 6, lane = threadIdx.x & 63;
    int node = blockIdx.x*4 + wave;
    int start = row_ptr[node], end = row_ptr[node+1];
    // Phase A: per-head max (lane-parallel over edges)
    float mx[8];
    #pragma unroll
    for (int h=0;h<8;++h) mx[h] = -INFINITY;
    for (int i = start + lane; i < end; i += 64){
        int e = eids[i];
        float4 l0 = *(const float4*)&logits[(size_t)e*8];
        float4 l1 = *(const float4*)&logits[(size_t)e*8+4];
        mx[0]=fmaxf(mx[0],l0.x); mx[1]=fmaxf(mx[1],l0.y);
        mx[2]=fmaxf(mx[2],l0.z); mx[3]=fmaxf(mx[3],l0.w);
        mx[4]=fmaxf(mx[4],l1.x); mx[5]=fmaxf(mx[5],l1.y);
        mx[6]=fmaxf(mx[6],l1.z); mx[7]=fmaxf(mx[7],l1.w);
    }
    #pragma unroll
    for (int d=1; d<64; d<<=1){
        #pragma unroll
        for (int h=0;h<8;++h) mx[h] = fmaxf(mx[h], __shfl_xor(mx[h], d));
    }
    // Phase B: exp + sum, store exp back into logits (each edge owned by exactly one wave)
    float sm[8] = {0.f,0.f,0.f,0.f,0.f,0.f,0.f,0.f};
    for (int i = start + lane; i < end; i += 64){
        int e = eids[i];
        float4 l0 = *(const float4*)&logits[(size_t)e*8];
        float4 l1 = *(const float4*)&logits[(size_t)e*8+4];
        l0.x = expf(l0.x - mx[0]); l0.y = expf(l0.y - mx[1]);
        l0.z = expf(l0.z - mx[2]); l0.w = expf(l0.w - mx[3]);
        l1.x = expf(l1.x - mx[4]); l1.y = expf(l1.y - mx[5]);
        l1.z = expf(l1.z - mx[6]); l1.w = expf(l1.w - mx[7]);
        sm[0]+=l0.x; sm[1]+=l0.y; sm[2]+=l0.z; sm[3]+=l0.w;
        sm[4]+=l1.x; sm[5]+=l1.y; sm[6]+=l1.z; sm[7]+=l1.w;
        *(float4*)&logits[(size_t)e*8]   = l0;
        *(float4*)&logits[(size_t)e*8+4] = l1;
    }
    #pragma unroll
    for (int d=1; d<64; d<<=1){
        #pragma unroll
        for (int h=0;h<8;++h) sm[h] += __shfl_xor(sm[h], d);
    }
    __syncthreads();   // drain the exp stores (vmcnt) so cross-lane reads below see them
    // Phase C: weighted accumulation, lane owns 4 contiguous output dims
    int h = lane >> 3;
    float rs = 1.0f / fmaxf(sm[h], 1e-16f);
    int co = lane * 4;
    float4 acc = {0.f,0.f,0.f,0.f};
    for (int i = start; i < end; ++i){
        int e = eids[i];
        float w = logits[(size_t)e*8 + h] * rs;
        int src = esrc[e];
        const float* vr = (e < EE) ? vr0 : vr1;
        float4 vv = *(const float4*)&vr[(size_t)src*256 + co];
        acc.x += w*vv.x; acc.y += w*vv.y; acc.z += w*vv.z; acc.w += w*vv.w;
    }
    *(float4*)&agg[(size_t)node*256 + co] = acc;
}

// ======================= K5: fused out GEMM + skip + (relu+LN) =======================
// h_out = blend(gelu(agg) @ W + b, h_in);  DO_LN: relu then layernorm
template<int DO_LN>
__global__ __launch_bounds__(256,2) void out_fused_k(const float* __restrict__ agg,
        const float* __restrict__ W, const float* __restrict__ bias,
        const float* __restrict__ h_in, const float* __restrict__ skip_l,
        const float* __restrict__ g, const float* __restrict__ b,
        float* __restrict__ h_out){
    __shared__ float As[16][68];     // [kk][row], gelu applied at stage
    __shared__ float Bs[16][260];    // [kk][col]
    __shared__ float rsum[64][33];
    __shared__ float rsq[64][33];
    __shared__ float mu_s[64], rstd_s[64];
    int tid = threadIdx.x;
    int row0 = blockIdx.x*64;
    int tx = tid & 31, ty = tid >> 5;   // tx: 32 col-groups of 8, ty: 8 row-groups of 8
    float acc[8][8];
    #pragma unroll
    for (int i=0;i<8;++i)
        #pragma unroll
        for (int j=0;j<8;++j) acc[i][j]=0.f;

    for (int k0=0; k0<256; k0+=16){
        {
            int r = tid >> 2, kc = (tid & 3) << 2;
            int grow = row0 + r;
            float4 v = {0.f,0.f,0.f,0.f};
            if (grow < NN) v = *(const float4*)&agg[(size_t)grow*256 + k0 + kc];
            As[kc+0][r] = gelu_exact(v.x);
            As[kc+1][r] = gelu_exact(v.y);
            As[kc+2][r] = gelu_exact(v.z);
            As[kc+3][r] = gelu_exact(v.w);
            #pragma unroll
            for (int it=0; it<4; ++it){
                int idx = it*256 + tid;
                int kk = idx >> 6, c = (idx & 63) << 2;
                *(float4*)&Bs[kk][c] = *(const float4*)&W[(size_t)(k0+kk)*256 + c];
            }
        }
        __syncthreads();
        #pragma unroll
        for (int kk=0; kk<16; ++kk){
            float a[8], bb[8];
            *(float4*)&a[0]  = *(const float4*)&As[kk][ty*8];
            *(float4*)&a[4]  = *(const float4*)&As[kk][ty*8+4];
            *(float4*)&bb[0] = *(const float4*)&Bs[kk][tx*8];
            *(float4*)&bb[4] = *(const float4*)&Bs[kk][tx*8+4];
            #pragma unroll
            for (int i=0;i<8;++i)
                #pragma unroll
                for (int j=0;j<8;++j) acc[i][j] += a[i]*bb[j];
        }
        __syncthreads();
    }

    float s = 1.f/(1.f+expf(-skip_l[0]));
    float os = 1.f - s;
    #pragma unroll
    for (int i=0;i<8;++i){
        int grow = row0 + ty*8 + i;
        float hv[8] = {0.f,0.f,0.f,0.f,0.f,0.f,0.f,0.f};
        if (grow < NN){
            *(float4*)&hv[0] = *(const float4*)&h_in[(size_t)grow*256 + tx*8];
            *(float4*)&hv[4] = *(const float4*)&h_in[(size_t)grow*256 + tx*8 + 4];
        }
        #pragma unroll
        for (int j=0;j<8;++j){
            float ao = acc[i][j] + bias[tx*8+j];
            float val = s*ao + os*hv[j];
            if (DO_LN) val = fmaxf(val, 0.f);
            acc[i][j] = val;
        }
    }

    if (DO_LN){
        #pragma unroll
        for (int i=0;i<8;++i){
            float ps=0.f, pq=0.f;
            #pragma unroll
            for (int j=0;j<8;++j){ ps += acc[i][j]; pq += acc[i][j]*acc[i][j]; }
            rsum[ty*8+i][tx] = ps;
            rsq[ty*8+i][tx]  = pq;
        }
        __syncthreads();
        if (tid < 64){
            float S=0.f, Q=0.f;
            for (int t=0;t<32;++t){ S += rsum[tid][t]; Q += rsq[tid][t]; }
            float mu = S * (1.f/256.f);
            float var = Q * (1.f/256.f) - mu*mu;
            mu_s[tid] = mu;
            rstd_s[tid] = rsqrtf(var + 1e-5f);
        }
        __syncthreads();
        #pragma unroll
        for (int i=0;i<8;++i){
            int grow = row0 + ty*8 + i;
            if (grow >= NN) continue;
            float mu = mu_s[ty*8+i], rstd = rstd_s[ty*8+i];
            float o[8];
            #pragma unroll
            for (int j=0;j<8;++j){
                int col = tx*8+j;
                o[j] = (acc[i][j]-mu)*rstd*g[col] + b[col];
            }
            *(float4*)&h_out[(size_t)grow*256 + tx*8]     = *(float4*)&o[0];
            *(float4*)&h_out[(size_t)grow*256 + tx*8 + 4] = *(float4*)&o[4];
        }
    } else {
        #pragma unroll
        for (int i=0;i<8;++i){
            int grow = row0 + ty*8 + i;
            if (grow >= NN) continue;
            *(float4*)&h_out[(size_t)grow*256 + tx*8]     = *(float4*)&acc[i][0];
            *(float4*)&h_out[(size_t)grow*256 + tx*8 + 4] = *(float4*)&acc[i][4];
        }
    }
}

// ======================= host =======================
extern "C" void kernel_launch(void* const* d_in, const int* in_sizes, int n_in,
                              void* d_out, int out_size, void* d_ws, size_t ws_size,
                              hipStream_t stream){
    (void)in_sizes; (void)n_in; (void)out_size; (void)ws_size;
    const float* x     = (const float*)d_in[0];
    const int*   ei0   = (const int*)d_in[1];
    const int*   ei1   = (const int*)d_in[2];
    const float* kqv_w = (const float*)d_in[3];
    const float* kqv_b = (const float*)d_in[4];
    const float* out_w = (const float*)d_in[5];
    const float* out_b = (const float*)d_in[6];
    const float* skip  = (const float*)d_in[7];
    const float* krel  = (const float*)d_in[8];
    const float* vrel  = (const float*)d_in[9];
    const float* prel  = (const float*)d_in[10];
    const float* ln_g  = (const float*)d_in[11];
    const float* ln_b  = (const float*)d_in[12];
    float* outp = (float*)d_out;

    char* wp = (char*)d_ws;
    auto alloc = [&](size_t bytes)->void*{
        void* p = wp; wp += (bytes + 255) & ~(size_t)255; return p;
    };
    float* hA   = (float*)alloc((size_t)NN*CC*4);
    float* hB   = (float*)alloc((size_t)NN*CC*4);
    float* kbuf = (float*)alloc((size_t)NN*CC*4);
    float* qbuf = (float*)alloc((size_t)NN*CC*4);
    float* vbuf = (float*)alloc((size_t)NN*CC*4);
    float* kr0  = (float*)alloc((size_t)NN*CC*4);
    float* kr1  = (float*)alloc((size_t)NN*CC*4);
    float* vr0  = (float*)alloc((size_t)NN*CC*4);
    float* vr1  = (float*)alloc((size_t)NN*CC*4);
    int* cnt     = (int*)alloc((size_t)NN*4);
    int* incl    = (int*)alloc((size_t)NN*4);
    int* row_ptr = (int*)alloc((size_t)(NN+1)*4);
    int* cursor  = (int*)alloc((size_t)NN*4);
    int* bsum    = (int*)alloc(128*4);
    int* eids    = (int*)alloc((size_t)TE*4);
    int* esrc    = (int*)alloc((size_t)TE*4);
    float* agg    = kbuf;   // k dead after rel_transform
    float* logits = vbuf;   // v dead after rel_transform (TE*8*4 = 10.2MB <= 20.5MB)

    // CSR build (edge lists are constant inputs; rebuilt every call for graph replay)
    hipMemsetAsync(cnt, 0, (size_t)NN*4, stream);
    hipMemsetAsync(cursor, 0, (size_t)NN*4, stream);
    hist_k<<<1250,256,0,stream>>>(ei0, ei1, cnt);
    scan_block_k<<<79,256,0,stream>>>(cnt, incl, bsum);
    scan_bsum_k<<<1,64,0,stream>>>(bsum, 79);
    finalize_rowptr_k<<<79,256,0,stream>>>(cnt, incl, bsum, row_ptr);
    scatter_k<<<1250,256,0,stream>>>(ei0, ei1, row_ptr, cursor, eids, esrc);

    const float* h_in = x;
    float* houts[4] = {hA, hB, hA, outp};
    for (int l=0; l<4; ++l){
        gemm_kqv_k<<<dim3(157,6),256,0,stream>>>(h_in, kqv_w + (size_t)l*196608,
                                                 kqv_b + l*768, kbuf, qbuf, vbuf);
        rel_transform_k<<<dim3(2500,8,4),256,0,stream>>>(kbuf, vbuf,
                krel + (size_t)l*16384, vrel + (size_t)l*16384, kr0, kr1, vr0, vr1);
        edge_logits_k<<<80000,256,0,stream>>>(qbuf, kr0, kr1, ei0, ei1,
                                              prel + l*16, logits);
        node_agg_k<<<5000,256,0,stream>>>(logits, vr0, vr1, row_ptr, eids, esrc, agg);
        if (l < 3)
            out_fused_k<1><<<313,256,0,stream>>>(agg, out_w + (size_t)l*65536,
                    out_b + l*256, h_in, skip + l, ln_g + l*256, ln_b + l*256, houts[l]);
        else
            out_fused_k<0><<<313,256,0,stream>>>(agg, out_w + (size_t)l*65536,
                    out_b + l*256, h_in, skip + l, ln_g, ln_b, houts[l]);
        h_in = houts[l];
    }
}

// Round 2
// 852.552 us; speedup vs baseline: 2.0640x; 2.0640x over previous
//
#include <hip/hip_runtime.h>
#include <math.h>

#define NN 20000
#define NPAD 20096          // padded rows for unguarded MFMA staging
#define CC 256
#define HH 8
#define EE 160000
#define TE 320000

typedef unsigned short u16;
typedef __attribute__((ext_vector_type(8))) short bf16x8;
typedef __attribute__((ext_vector_type(4))) float f32x4;

__device__ __forceinline__ float gelu_exact(float x){
    return 0.5f*x*(1.0f+erff(x*0.7071067811865476f));
}
__device__ __forceinline__ u16 f2bf(float f){
    unsigned u = __float_as_uint(f);
    unsigned r = (u + 0x7fffu + ((u >> 16) & 1u)) >> 16;
    return (u16)r;
}
__device__ __forceinline__ float bf2f(u16 s){
    return __uint_as_float(((unsigned)s) << 16);
}
__device__ __forceinline__ void gload_lds16(const u16* gsrc, u16* lds_dst){
    __builtin_amdgcn_global_load_lds((const __attribute__((address_space(1))) unsigned int*)gsrc,
                                     (__attribute__((address_space(3))) unsigned int*)lds_dst,
                                     16, 0, 0);
}

// ======================= CSR build =======================
__global__ void hist_k(const int* __restrict__ ei0, const int* __restrict__ ei1,
                       int* __restrict__ cnt){
    int e = blockIdx.x*256 + threadIdx.x;
    if (e < TE){
        int dst = (e < EE) ? ei0[EE + e] : ei1[EE + (e - EE)];
        atomicAdd(&cnt[dst], 1);
    }
}
__global__ void scan_block_k(const int* __restrict__ cnt, int* __restrict__ incl,
                             int* __restrict__ bsum){
    __shared__ int tmp[256];
    int tid = threadIdx.x;
    int i = blockIdx.x*256 + tid;
    int v = (i < NN) ? cnt[i] : 0;
    tmp[tid] = v;
    __syncthreads();
    for (int d=1; d<256; d<<=1){
        int t = (tid>=d) ? tmp[tid-d] : 0;
        __syncthreads();
        tmp[tid] += t;
        __syncthreads();
    }
    if (i < NN) incl[i] = tmp[tid];
    if (tid == 255) bsum[blockIdx.x] = tmp[255];
}
__global__ void scan_bsum_k(int* bsum, int nb){
    if (threadIdx.x==0 && blockIdx.x==0){
        int acc = 0;
        for (int i=0;i<nb;++i){ int t=bsum[i]; bsum[i]=acc; acc+=t; }
    }
}
__global__ void finalize_rowptr_k(const int* __restrict__ cnt, const int* __restrict__ incl,
                                  const int* __restrict__ bsum, int* __restrict__ row_ptr){
    int i = blockIdx.x*256 + threadIdx.x;
    if (i < NN) row_ptr[i] = incl[i] - cnt[i] + bsum[blockIdx.x];
    if (i == NN) row_ptr[NN] = TE;
}
// packs src | rel<<30 per CSR slot (kills the eids->esrc dependent gather)
__global__ void scatter_k(const int* __restrict__ ei0, const int* __restrict__ ei1,
                          const int* __restrict__ row_ptr, int* __restrict__ cursor,
                          int* __restrict__ epk){
    int e = blockIdx.x*256 + threadIdx.x;
    if (e < TE){
        int src, dst, rel;
        if (e < EE){ src = ei0[e]; dst = ei0[EE+e]; rel = 0; }
        else { int ee=e-EE; src = ei1[ee]; dst = ei1[EE+ee]; rel = 1; }
        int pos = atomicAdd(&cursor[dst], 1);
        epk[row_ptr[dst] + pos] = src | (rel << 30);
    }
}

// ======================= weight prep =======================
// Wt5[l][n][k] (bf16, k-contiguous = transposed for MFMA B staging), n in [0,1280):
//   n<256: q weights; 256..511: kr0; 512..767: kr1; 768..1023: vr0; 1024..1279: vr1
// kqv split order in reference: k=cols[0,256), q=[256,512), v=[512,768)
__global__ void build_w5_k(const float* __restrict__ kqv_w, const float* __restrict__ krel,
                           const float* __restrict__ vrel, u16* __restrict__ Wt){
    int idx = blockIdx.x*256 + threadIdx.x;        // 4*1280*256
    int k = idx & 255;
    int n = (idx >> 8) % 1280;
    int l = idx / (1280*256);
    const float* W = kqv_w + (size_t)l*196608;     // [256][768]
    float val;
    if (n < 256){
        val = W[k*768 + 256 + n];
    } else {
        int g = (n-256) >> 8;
        int r = g & 1, isv = g >> 1;
        int c = (n-256) & 255;
        int h = c >> 5, f = c & 31;
        const float* Rm = (isv ? vrel : krel) + ((size_t)l*2 + r)*8192 + h*1024; // [32][32]
        int base = isv ? 512 : 0;
        float a = 0.f;
        #pragma unroll 8
        for (int d=0; d<32; ++d)
            a += W[k*768 + base + h*32 + d] * Rm[d*32 + f];
        val = a;
    }
    Wt[(size_t)l*327680 + (size_t)n*256 + k] = f2bf(val);
}
__global__ void build_bias5_k(const float* __restrict__ kqv_b, const float* __restrict__ krel,
                              const float* __restrict__ vrel, float* __restrict__ bias5){
    int idx = blockIdx.x*256 + threadIdx.x;        // 4*1280
    if (idx >= 4*1280) return;
    int n = idx % 1280, l = idx / 1280;
    const float* B = kqv_b + l*768;
    float val;
    if (n < 256) val = B[256+n];
    else {
        int g = (n-256) >> 8;
        int r = g & 1, isv = g >> 1;
        int c = (n-256) & 255;
        int h = c >> 5, f = c & 31;
        const float* Rm = (isv ? vrel : krel) + ((size_t)l*2 + r)*8192 + h*1024;
        int base = isv ? 512 : 0;
        float a = 0.f;
        for (int d=0; d<32; ++d) a += B[base + h*32 + d] * Rm[d*32 + f];
        val = a;
    }
    bias5[idx] = val;
}
__global__ void cvt_x_k(const float* __restrict__ x, u16* __restrict__ xbf){
    int idx = blockIdx.x*256 + threadIdx.x;        // 640000 (8 elems each)
    const float4* xp = (const float4*)x;
    float4 a = xp[(size_t)idx*2], b = xp[(size_t)idx*2+1];
    uint4 o;
    o.x = (unsigned)f2bf(a.x) | ((unsigned)f2bf(a.y)<<16);
    o.y = (unsigned)f2bf(a.z) | ((unsigned)f2bf(a.w)<<16);
    o.z = (unsigned)f2bf(b.x) | ((unsigned)f2bf(b.y)<<16);
    o.w = (unsigned)f2bf(b.z) | ((unsigned)f2bf(b.w)<<16);
    *(uint4*)&xbf[(size_t)idx*8] = o;
}

// ======================= K1: 5-output MFMA GEMM =======================
// [NPAD,256]bf16 @ Wt'[1280,256]bf16(T) -> q,kr0,kr1,vr0,vr1 bf16 [NN,256]
__global__ __launch_bounds__(256) void gemm5_k(const u16* __restrict__ A,
        const u16* __restrict__ Wt, const float* __restrict__ biasp,
        u16* __restrict__ qb, u16* __restrict__ kr0b, u16* __restrict__ kr1b,
        u16* __restrict__ vr0b, u16* __restrict__ vr1b){
    __shared__ u16 As[4096];   // 128 rows x 32 k (16B slots, XOR-swizzled)
    __shared__ u16 Bs[4096];
    int tid = threadIdx.x;
    int w = tid >> 6, lane = tid & 63;
    int row0 = blockIdx.x * 128;
    int col0 = blockIdx.y * 128;
    int wm = w & 1, wn = w >> 1;
    f32x4 acc[4][4];
    #pragma unroll
    for (int i=0;i<4;++i)
        #pragma unroll
        for (int j=0;j<4;++j) acc[i][j] = (f32x4){0.f,0.f,0.f,0.f};

    int lm = lane & 15, quad = lane >> 4;
    int kq0 = quad ^ (lm & 3);                 // read-side swizzle (row&3 == lm&3)
    int aoff = (wm*64 + lm)*32 + kq0*8;
    int boff = (wn*64 + lm)*32 + kq0*8;

    for (int k0 = 0; k0 < 256; k0 += 32){
        #pragma unroll
        for (int it = 0; it < 2; ++it){
            int s = w*128 + it*64 + lane;      // 16B slot id
            int row = s >> 2, q0 = s & 3;
            int kq = q0 ^ (row & 3);           // write-side swizzle via global source addr
            gload_lds16(&A [(size_t)(row0+row)*256 + k0 + kq*8], &As[(size_t)(w*128 + it*64)*8]);
            gload_lds16(&Wt[(size_t)(col0+row)*256 + k0 + kq*8], &Bs[(size_t)(w*128 + it*64)*8]);
        }
        __syncthreads();
        bf16x8 af[4], bfr[4];
        #pragma unroll
        for (int mi=0; mi<4; ++mi) af[mi]  = *(bf16x8*)&As[aoff + mi*512];
        #pragma unroll
        for (int ni=0; ni<4; ++ni) bfr[ni] = *(bf16x8*)&Bs[boff + ni*512];
        #pragma unroll
        for (int mi=0; mi<4; ++mi)
            #pragma unroll
            for (int ni=0; ni<4; ++ni)
                acc[mi][ni] = __builtin_amdgcn_mfma_f32_16x16x32_bf16(af[mi], bfr[ni], acc[mi][ni], 0,0,0);
        __syncthreads();
    }
    // epilogue: C/D layout col=lane&15, row=quad*4+reg
    int bufi = col0 >> 8;   // uniform per block (128-tile never straddles a 256 boundary)
    u16* obuf = (bufi==0)?qb:((bufi==1)?kr0b:((bufi==2)?kr1b:((bufi==3)?vr0b:vr1b)));
    #pragma unroll
    for (int ni=0; ni<4; ++ni){
        int colg = col0 + wn*64 + ni*16 + lm;
        float bv = biasp[colg];
        int cw = colg & 255;
        #pragma unroll
        for (int mi=0; mi<4; ++mi){
            #pragma unroll
            for (int t=0; t<4; ++t){
                int r = row0 + wm*64 + mi*16 + quad*4 + t;
                if (r < NN) obuf[(size_t)r*256 + cw] = f2bf(acc[mi][ni][t] + bv);
            }
        }
    }
}

// ======================= K2: fused CSR attention, online softmax =======================
// one wave per dst node; lanes 0-31 handle kr (logits), 32-63 handle vr (accum)
__global__ __launch_bounds__(256) void attn_k(const u16* __restrict__ qb,
        const u16* __restrict__ kr0b, const u16* __restrict__ kr1b,
        const u16* __restrict__ vr0b, const u16* __restrict__ vr1b,
        const int* __restrict__ row_ptr, const int* __restrict__ epk,
        const float* __restrict__ prel_l, u16* __restrict__ A2){
    int wv = threadIdx.x >> 6, lane = threadIdx.x & 63;
    int node = blockIdx.x*4 + wv;
    int l32 = lane & 31;
    bool isV = lane >= 32;
    int start = row_ptr[node], end = row_ptr[node+1];
    // q row (both half-waves hold the same 8 dims = l32*8..+8)
    float qf[8];
    {
        uint4 qr = *(const uint4*)&qb[(size_t)node*256 + l32*8];
        qf[0]=bf2f(qr.x&0xffff); qf[1]=bf2f(qr.x>>16);
        qf[2]=bf2f(qr.y&0xffff); qf[3]=bf2f(qr.y>>16);
        qf[4]=bf2f(qr.z&0xffff); qf[5]=bf2f(qr.z>>16);
        qf[6]=bf2f(qr.w&0xffff); qf[7]=bf2f(qr.w>>16);
    }
    int h = l32 >> 2;
    float p0 = prel_l[h], p1 = prel_l[8+h];
    float m = -INFINITY, s = 0.f;
    float acc[8] = {0.f,0.f,0.f,0.f,0.f,0.f,0.f,0.f};

    uint4 raw0 = {0,0,0,0};
    int rel0 = 0;
    if (start < end){
        unsigned p = (unsigned)epk[start];
        int src = p & 0x3FFFFFFF; rel0 = (int)(p >> 30);
        const u16* kb = rel0 ? kr1b : kr0b;
        const u16* vb = rel0 ? vr1b : vr0b;
        const u16* bb = isV ? vb : kb;
        raw0 = *(const uint4*)&bb[(size_t)src*256 + l32*8];
    }
    for (int i = start; i < end; ++i){
        uint4 raw1 = raw0; int rel1 = rel0;
        if (i+1 < end){                         // prefetch next edge's row
            unsigned p = (unsigned)epk[i+1];
            int src = p & 0x3FFFFFFF; rel1 = (int)(p >> 30);
            const u16* kb = rel1 ? kr1b : kr0b;
            const u16* vb = rel1 ? vr1b : vr0b;
            const u16* bb = isV ? vb : kb;
            raw1 = *(const uint4*)&bb[(size_t)src*256 + l32*8];
        }
        float kv[8];
        kv[0]=bf2f(raw0.x&0xffff); kv[1]=bf2f(raw0.x>>16);
        kv[2]=bf2f(raw0.y&0xffff); kv[3]=bf2f(raw0.y>>16);
        kv[4]=bf2f(raw0.z&0xffff); kv[5]=bf2f(raw0.z>>16);
        kv[6]=bf2f(raw0.w&0xffff); kv[7]=bf2f(raw0.w>>16);
        float p = qf[0]*kv[0]+qf[1]*kv[1]+qf[2]*kv[2]+qf[3]*kv[3]
                 +qf[4]*kv[4]+qf[5]*kv[5]+qf[6]*kv[6]+qf[7]*kv[7];
        p += __shfl_xor(p, 1);
        p += __shfl_xor(p, 2);                  // 4-lane head group reduced
        p = __shfl(p, l32);                     // mirror to upper half
        float logit = p * (rel0 ? p1 : p0) * 0.17677669529663687f;
        float mo = m; m = fmaxf(m, logit);
        float sc = __expf(mo - m);              // first edge: exp(-inf)=0
        float pe = __expf(logit - m);
        s = s*sc + pe;
        #pragma unroll
        for (int j=0;j<8;++j) acc[j] = acc[j]*sc + pe*kv[j];
        raw0 = raw1; rel0 = rel1;
    }
    if (isV){
        float rs = 1.f / fmaxf(s, 1e-16f);
        u16 o[8];
        #pragma unroll
        for (int j=0;j<8;++j) o[j] = f2bf(gelu_exact(acc[j]*rs));
        uint4 ov;
        ov.x = (unsigned)o[0] | ((unsigned)o[1]<<16);
        ov.y = (unsigned)o[2] | ((unsigned)o[3]<<16);
        ov.z = (unsigned)o[4] | ((unsigned)o[5]<<16);
        ov.w = (unsigned)o[6] | ((unsigned)o[7]<<16);
        *(uint4*)&A2[(size_t)node*256 + l32*8] = ov;
    }
}

// ======================= K3: out GEMM (fp32) + skip + (relu+LN) =======================
// A2 = bf16(gelu(agg)) already activated; h_out = s*(A2f@W + b) + (1-s)*h_in
template<int DO_LN>
__global__ __launch_bounds__(256,2) void out_fused_k(const u16* __restrict__ A2,
        const float* __restrict__ W, const float* __restrict__ bias,
        const float* __restrict__ h_in, const float* __restrict__ skip_l,
        const float* __restrict__ g, const float* __restrict__ b,
        float* __restrict__ h_out, u16* __restrict__ hbf){
    __shared__ float As[16][68];
    __shared__ float Bs[16][260];
    __shared__ float rsum[64][33];
    __shared__ float rsq[64][33];
    __shared__ float mu_s[64], rstd_s[64];
    int tid = threadIdx.x;
    int row0 = blockIdx.x*64;
    int tx = tid & 31, ty = tid >> 5;
    float acc[8][8];
    #pragma unroll
    for (int i=0;i<8;++i)
        #pragma unroll
        for (int j=0;j<8;++j) acc[i][j]=0.f;

    for (int k0=0; k0<256; k0+=16){
        {
            int r = tid >> 2, kc = (tid & 3) << 2;
            int grow = row0 + r;
            ushort4 v = {0,0,0,0};
            if (grow < NN) v = *(const ushort4*)&A2[(size_t)grow*256 + k0 + kc];
            As[kc+0][r] = bf2f(v.x);
            As[kc+1][r] = bf2f(v.y);
            As[kc+2][r] = bf2f(v.z);
            As[kc+3][r] = bf2f(v.w);
            #pragma unroll
            for (int it=0; it<4; ++it){
                int idx = it*256 + tid;
                int kk = idx >> 6, c = (idx & 63) << 2;
                *(float4*)&Bs[kk][c] = *(const float4*)&W[(size_t)(k0+kk)*256 + c];
            }
        }
        __syncthreads();
        #pragma unroll
        for (int kk=0; kk<16; ++kk){
            float a[8], bb[8];
            *(float4*)&a[0]  = *(const float4*)&As[kk][ty*8];
            *(float4*)&a[4]  = *(const float4*)&As[kk][ty*8+4];
            *(float4*)&bb[0] = *(const float4*)&Bs[kk][tx*8];
            *(float4*)&bb[4] = *(const float4*)&Bs[kk][tx*8+4];
            #pragma unroll
            for (int i=0;i<8;++i)
                #pragma unroll
                for (int j=0;j<8;++j) acc[i][j] += a[i]*bb[j];
        }
        __syncthreads();
    }

    float s = 1.f/(1.f+expf(-skip_l[0]));
    float os = 1.f - s;
    #pragma unroll
    for (int i=0;i<8;++i){
        int grow = row0 + ty*8 + i;
        float hv[8] = {0.f,0.f,0.f,0.f,0.f,0.f,0.f,0.f};
        if (grow < NN){
            *(float4*)&hv[0] = *(const float4*)&h_in[(size_t)grow*256 + tx*8];
            *(float4*)&hv[4] = *(const float4*)&h_in[(size_t)grow*256 + tx*8 + 4];
        }
        #pragma unroll
        for (int j=0;j<8;++j){
            float ao = acc[i][j] + bias[tx*8+j];
            float val = s*ao + os*hv[j];
            if (DO_LN) val = fmaxf(val, 0.f);
            acc[i][j] = val;
        }
    }

    if (DO_LN){
        #pragma unroll
        for (int i=0;i<8;++i){
            float ps=0.f, pq=0.f;
            #pragma unroll
            for (int j=0;j<8;++j){ ps += acc[i][j]; pq += acc[i][j]*acc[i][j]; }
            rsum[ty*8+i][tx] = ps;
            rsq[ty*8+i][tx]  = pq;
        }
        __syncthreads();
        if (tid < 64){
            float S=0.f, Q=0.f;
            for (int t=0;t<32;++t){ S += rsum[tid][t]; Q += rsq[tid][t]; }
            float mu = S * (1.f/256.f);
            float var = Q * (1.f/256.f) - mu*mu;
            mu_s[tid] = mu;
            rstd_s[tid] = rsqrtf(var + 1e-5f);
        }
        __syncthreads();
        #pragma unroll
        for (int i=0;i<8;++i){
            int grow = row0 + ty*8 + i;
            if (grow >= NN) continue;
            float mu = mu_s[ty*8+i], rstd = rstd_s[ty*8+i];
            float o[8];
            u16 ob[8];
            #pragma unroll
            for (int j=0;j<8;++j){
                int col = tx*8+j;
                o[j] = (acc[i][j]-mu)*rstd*g[col] + b[col];
                ob[j] = f2bf(o[j]);
            }
            *(float4*)&h_out[(size_t)grow*256 + tx*8]     = *(float4*)&o[0];
            *(float4*)&h_out[(size_t)grow*256 + tx*8 + 4] = *(float4*)&o[4];
            uint4 ov;
            ov.x = (unsigned)ob[0] | ((unsigned)ob[1]<<16);
            ov.y = (unsigned)ob[2] | ((unsigned)ob[3]<<16);
            ov.z = (unsigned)ob[4] | ((unsigned)ob[5]<<16);
            ov.w = (unsigned)ob[6] | ((unsigned)ob[7]<<16);
            *(uint4*)&hbf[(size_t)grow*256 + tx*8] = ov;
        }
    } else {
        #pragma unroll
        for (int i=0;i<8;++i){
            int grow = row0 + ty*8 + i;
            if (grow >= NN) continue;
            *(float4*)&h_out[(size_t)grow*256 + tx*8]     = *(float4*)&acc[i][0];
            *(float4*)&h_out[(size_t)grow*256 + tx*8 + 4] = *(float4*)&acc[i][4];
        }
    }
}

// ======================= host =======================
extern "C" void kernel_launch(void* const* d_in, const int* in_sizes, int n_in,
                              void* d_out, int out_size, void* d_ws, size_t ws_size,
                              hipStream_t stream){
    (void)in_sizes; (void)n_in; (void)out_size; (void)ws_size;
    const float* x     = (const float*)d_in[0];
    const int*   ei0   = (const int*)d_in[1];
    const int*   ei1   = (const int*)d_in[2];
    const float* kqv_w = (const float*)d_in[3];
    const float* kqv_b = (const float*)d_in[4];
    const float* out_w = (const float*)d_in[5];
    const float* out_b = (const float*)d_in[6];
    const float* skip  = (const float*)d_in[7];
    const float* krel  = (const float*)d_in[8];
    const float* vrel  = (const float*)d_in[9];
    const float* prel  = (const float*)d_in[10];
    const float* ln_g  = (const float*)d_in[11];
    const float* ln_b  = (const float*)d_in[12];
    float* outp = (float*)d_out;

    char* wp = (char*)d_ws;
    auto alloc = [&](size_t bytes)->void*{
        void* p = wp; wp += (bytes + 255) & ~(size_t)255; return p;
    };
    float* hA    = (float*)alloc((size_t)NN*CC*4);
    float* hB    = (float*)alloc((size_t)NN*CC*4);
    u16*   xbf   = (u16*)alloc((size_t)NPAD*CC*2);
    u16*   hbf   = (u16*)alloc((size_t)NPAD*CC*2);
    u16*   A2    = (u16*)alloc((size_t)NPAD*CC*2);
    u16*   qb    = (u16*)alloc((size_t)NN*CC*2);
    u16*   kr0b  = (u16*)alloc((size_t)NN*CC*2);
    u16*   kr1b  = (u16*)alloc((size_t)NN*CC*2);
    u16*   vr0b  = (u16*)alloc((size_t)NN*CC*2);
    u16*   vr1b  = (u16*)alloc((size_t)NN*CC*2);
    u16*   Wt5   = (u16*)alloc((size_t)4*1280*256*2);
    float* bias5 = (float*)alloc((size_t)4*1280*4);
    int* cnt     = (int*)alloc((size_t)NN*4);
    int* incl    = (int*)alloc((size_t)NN*4);
    int* row_ptr = (int*)alloc((size_t)(NN+1)*4);
    int* cursor  = (int*)alloc((size_t)NN*4);
    int* bsum    = (int*)alloc(128*4);
    int* epk     = (int*)alloc((size_t)TE*4);

    // prep (weights + input cast) — independent of CSR chain
    build_w5_k<<<5120,256,0,stream>>>(kqv_w, krel, vrel, Wt5);
    build_bias5_k<<<20,256,0,stream>>>(kqv_b, krel, vrel, bias5);
    cvt_x_k<<<2500,256,0,stream>>>(x, xbf);

    // CSR build
    hipMemsetAsync(cnt, 0, (size_t)NN*4, stream);
    hipMemsetAsync(cursor, 0, (size_t)NN*4, stream);
    hist_k<<<1250,256,0,stream>>>(ei0, ei1, cnt);
    scan_block_k<<<79,256,0,stream>>>(cnt, incl, bsum);
    scan_bsum_k<<<1,64,0,stream>>>(bsum, 79);
    finalize_rowptr_k<<<79,256,0,stream>>>(cnt, incl, bsum, row_ptr);
    scatter_k<<<1250,256,0,stream>>>(ei0, ei1, row_ptr, cursor, epk);

    const float* h_in = x;
    const u16*   Ain  = xbf;
    float* houts[4] = {hA, hB, hA, outp};
    for (int l=0; l<4; ++l){
        gemm5_k<<<dim3(157,10),256,0,stream>>>(Ain, Wt5 + (size_t)l*327680,
                bias5 + l*1280, qb, kr0b, kr1b, vr0b, vr1b);
        attn_k<<<5000,256,0,stream>>>(qb, kr0b, kr1b, vr0b, vr1b,
                row_ptr, epk, prel + l*16, A2);
        if (l < 3)
            out_fused_k<1><<<313,256,0,stream>>>(A2, out_w + (size_t)l*65536,
                    out_b + l*256, h_in, skip + l, ln_g + l*256, ln_b + l*256,
                    houts[l], hbf);
        else
            out_fused_k<0><<<313,256,0,stream>>>(A2, out_w + (size_t)l*65536,
                    out_b + l*256, h_in, skip + l, ln_g, ln_b, houts[l], hbf);
        h_in = houts[l];
        Ain = hbf;
    }
}

// Round 4
// 755.917 us; speedup vs baseline: 2.3279x; 1.1278x over previous
//
#include <hip/hip_runtime.h>
#include <math.h>

#define NN 20000
#define NPAD 20096          // padded rows for unguarded MFMA staging
#define CC 256
#define HH 8
#define EE 160000
#define TE 320000

typedef unsigned short u16;
typedef __attribute__((ext_vector_type(8))) short bf16x8;
typedef __attribute__((ext_vector_type(4))) float f32x4;

__device__ __forceinline__ float gelu_exact(float x){
    return 0.5f*x*(1.0f+erff(x*0.7071067811865476f));
}
__device__ __forceinline__ u16 f2bf(float f){
    unsigned u = __float_as_uint(f);
    unsigned r = (u + 0x7fffu + ((u >> 16) & 1u)) >> 16;
    return (u16)r;
}
__device__ __forceinline__ float bf2f(u16 s){
    return __uint_as_float(((unsigned)s) << 16);
}
__device__ __forceinline__ void gload_lds16(const u16* gsrc, u16* lds_dst){
    __builtin_amdgcn_global_load_lds((const __attribute__((address_space(1))) unsigned int*)gsrc,
                                     (__attribute__((address_space(3))) unsigned int*)lds_dst,
                                     16, 0, 0);
}

// ======================= CSR build =======================
__global__ void hist_k(const int* __restrict__ ei0, const int* __restrict__ ei1,
                       int* __restrict__ cnt){
    int e = blockIdx.x*256 + threadIdx.x;
    if (e < TE){
        int dst = (e < EE) ? ei0[EE + e] : ei1[EE + (e - EE)];
        atomicAdd(&cnt[dst], 1);
    }
}
__global__ void scan_block_k(const int* __restrict__ cnt, int* __restrict__ incl,
                             int* __restrict__ bsum){
    __shared__ int tmp[256];
    int tid = threadIdx.x;
    int i = blockIdx.x*256 + tid;
    int v = (i < NN) ? cnt[i] : 0;
    tmp[tid] = v;
    __syncthreads();
    for (int d=1; d<256; d<<=1){
        int t = (tid>=d) ? tmp[tid-d] : 0;
        __syncthreads();
        tmp[tid] += t;
        __syncthreads();
    }
    if (i < NN) incl[i] = tmp[tid];
    if (tid == 255) bsum[blockIdx.x] = tmp[255];
}
__global__ void scan_bsum_k(int* bsum, int nb){
    if (threadIdx.x==0 && blockIdx.x==0){
        int acc = 0;
        for (int i=0;i<nb;++i){ int t=bsum[i]; bsum[i]=acc; acc+=t; }
    }
}
__global__ void finalize_rowptr_k(const int* __restrict__ cnt, const int* __restrict__ incl,
                                  const int* __restrict__ bsum, int* __restrict__ row_ptr){
    int i = blockIdx.x*256 + threadIdx.x;
    if (i < NN) row_ptr[i] = incl[i] - cnt[i] + bsum[blockIdx.x];
    if (i == NN) row_ptr[NN] = TE;
}
// packs src | rel<<30 per CSR slot
__global__ void scatter_k(const int* __restrict__ ei0, const int* __restrict__ ei1,
                          const int* __restrict__ row_ptr, int* __restrict__ cursor,
                          int* __restrict__ epk){
    int e = blockIdx.x*256 + threadIdx.x;
    if (e < TE){
        int src, dst, rel;
        if (e < EE){ src = ei0[e]; dst = ei0[EE+e]; rel = 0; }
        else { int ee=e-EE; src = ei1[ee]; dst = ei1[EE+ee]; rel = 1; }
        int pos = atomicAdd(&cursor[dst], 1);
        epk[row_ptr[dst] + pos] = src | (rel << 30);
    }
}

// ======================= weight prep =======================
__global__ void build_w5_k(const float* __restrict__ kqv_w, const float* __restrict__ krel,
                           const float* __restrict__ vrel, u16* __restrict__ Wt){
    int idx = blockIdx.x*256 + threadIdx.x;        // 4*1280*256
    int k = idx & 255;
    int n = (idx >> 8) % 1280;
    int l = idx / (1280*256);
    const float* W = kqv_w + (size_t)l*196608;     // [256][768]
    float val;
    if (n < 256){
        val = W[k*768 + 256 + n];
    } else {
        int g = (n-256) >> 8;
        int r = g & 1, isv = g >> 1;
        int c = (n-256) & 255;
        int h = c >> 5, f = c & 31;
        const float* Rm = (isv ? vrel : krel) + ((size_t)l*2 + r)*8192 + h*1024; // [32][32]
        int base = isv ? 512 : 0;
        float a = 0.f;
        #pragma unroll 8
        for (int d=0; d<32; ++d)
            a += W[k*768 + base + h*32 + d] * Rm[d*32 + f];
        val = a;
    }
    Wt[(size_t)l*327680 + (size_t)n*256 + k] = f2bf(val);
}
__global__ void build_bias5_k(const float* __restrict__ kqv_b, const float* __restrict__ krel,
                              const float* __restrict__ vrel, float* __restrict__ bias5){
    int idx = blockIdx.x*256 + threadIdx.x;        // 4*1280
    if (idx >= 4*1280) return;
    int n = idx % 1280, l = idx / 1280;
    const float* B = kqv_b + l*768;
    float val;
    if (n < 256) val = B[256+n];
    else {
        int g = (n-256) >> 8;
        int r = g & 1, isv = g >> 1;
        int c = (n-256) & 255;
        int h = c >> 5, f = c & 31;
        const float* Rm = (isv ? vrel : krel) + ((size_t)l*2 + r)*8192 + h*1024;
        int base = isv ? 512 : 0;
        float a = 0.f;
        for (int d=0; d<32; ++d) a += B[base + h*32 + d] * Rm[d*32 + f];
        val = a;
    }
    bias5[idx] = val;
}
// transpose out_w [l][k][n] fp32 -> Wto [l][n][k] bf16
__global__ void build_wo_k(const float* __restrict__ out_w, u16* __restrict__ Wto){
    int idx = blockIdx.x*256 + threadIdx.x;        // 4*256*256
    int k = idx & 255;
    int n = (idx >> 8) & 255;
    int l = idx >> 16;
    Wto[(size_t)l*65536 + n*256 + k] = f2bf(out_w[(size_t)l*65536 + k*256 + n]);
}
__global__ void cvt_x_k(const float* __restrict__ x, u16* __restrict__ xbf){
    int idx = blockIdx.x*256 + threadIdx.x;        // 640000 (8 elems each)
    const float4* xp = (const float4*)x;
    float4 a = xp[(size_t)idx*2], b = xp[(size_t)idx*2+1];
    uint4 o;
    o.x = (unsigned)f2bf(a.x) | ((unsigned)f2bf(a.y)<<16);
    o.y = (unsigned)f2bf(a.z) | ((unsigned)f2bf(a.w)<<16);
    o.z = (unsigned)f2bf(b.x) | ((unsigned)f2bf(b.y)<<16);
    o.w = (unsigned)f2bf(b.z) | ((unsigned)f2bf(b.w)<<16);
    *(uint4*)&xbf[(size_t)idx*8] = o;
}

// ======================= K1: 5-output MFMA GEMM =======================
__global__ __launch_bounds__(256) void gemm5_k(const u16* __restrict__ A,
        const u16* __restrict__ Wt, const float* __restrict__ biasp,
        u16* __restrict__ qb, u16* __restrict__ kr0b, u16* __restrict__ kr1b,
        u16* __restrict__ vr0b, u16* __restrict__ vr1b){
    __shared__ u16 As[4096];   // 128 rows x 32 k (16B slots, XOR-swizzled)
    __shared__ u16 Bs[4096];
    int tid = threadIdx.x;
    int w = tid >> 6, lane = tid & 63;
    int row0 = blockIdx.x * 128;
    int col0 = blockIdx.y * 128;
    int wm = w & 1, wn = w >> 1;
    f32x4 acc[4][4];
    #pragma unroll
    for (int i=0;i<4;++i)
        #pragma unroll
        for (int j=0;j<4;++j) acc[i][j] = (f32x4){0.f,0.f,0.f,0.f};

    int lm = lane & 15, quad = lane >> 4;
    int kq0 = quad ^ (lm & 3);
    int aoff = (wm*64 + lm)*32 + kq0*8;
    int boff = (wn*64 + lm)*32 + kq0*8;

    for (int k0 = 0; k0 < 256; k0 += 32){
        #pragma unroll
        for (int it = 0; it < 2; ++it){
            int s = w*128 + it*64 + lane;      // 16B slot id
            int row = s >> 2, q0 = s & 3;
            int kq = q0 ^ (row & 3);
            gload_lds16(&A [(size_t)(row0+row)*256 + k0 + kq*8], &As[(size_t)(w*128 + it*64)*8]);
            gload_lds16(&Wt[(size_t)(col0+row)*256 + k0 + kq*8], &Bs[(size_t)(w*128 + it*64)*8]);
        }
        __syncthreads();
        bf16x8 af[4], bfr[4];
        #pragma unroll
        for (int mi=0; mi<4; ++mi) af[mi]  = *(bf16x8*)&As[aoff + mi*512];
        #pragma unroll
        for (int ni=0; ni<4; ++ni) bfr[ni] = *(bf16x8*)&Bs[boff + ni*512];
        #pragma unroll
        for (int mi=0; mi<4; ++mi)
            #pragma unroll
            for (int ni=0; ni<4; ++ni)
                acc[mi][ni] = __builtin_amdgcn_mfma_f32_16x16x32_bf16(af[mi], bfr[ni], acc[mi][ni], 0,0,0);
        __syncthreads();
    }
    int bufi = col0 >> 8;
    u16* obuf = (bufi==0)?qb:((bufi==1)?kr0b:((bufi==2)?kr1b:((bufi==3)?vr0b:vr1b)));
    #pragma unroll
    for (int ni=0; ni<4; ++ni){
        int colg = col0 + wn*64 + ni*16 + lm;
        float bv = biasp[colg];
        int cw = colg & 255;
        #pragma unroll
        for (int mi=0; mi<4; ++mi){
            #pragma unroll
            for (int t=0; t<4; ++t){
                int r = row0 + wm*64 + mi*16 + quad*4 + t;
                if (r < NN) obuf[(size_t)r*256 + cw] = f2bf(acc[mi][ni][t] + bv);
            }
        }
    }
}

// ======================= K2: fused CSR attention, online softmax =======================
__global__ __launch_bounds__(256) void attn_k(const u16* __restrict__ qb,
        const u16* __restrict__ kr0b, const u16* __restrict__ kr1b,
        const u16* __restrict__ vr0b, const u16* __restrict__ vr1b,
        const int* __restrict__ row_ptr, const int* __restrict__ epk,
        const float* __restrict__ prel_l, u16* __restrict__ A2){
    int wv = threadIdx.x >> 6, lane = threadIdx.x & 63;
    int node = blockIdx.x*4 + wv;
    int l32 = lane & 31;
    bool isV = lane >= 32;
    int start = row_ptr[node], end = row_ptr[node+1];
    float qf[8];
    {
        uint4 qr = *(const uint4*)&qb[(size_t)node*256 + l32*8];
        qf[0]=bf2f(qr.x&0xffff); qf[1]=bf2f(qr.x>>16);
        qf[2]=bf2f(qr.y&0xffff); qf[3]=bf2f(qr.y>>16);
        qf[4]=bf2f(qr.z&0xffff); qf[5]=bf2f(qr.z>>16);
        qf[6]=bf2f(qr.w&0xffff); qf[7]=bf2f(qr.w>>16);
    }
    int h = l32 >> 2;
    float p0 = prel_l[h], p1 = prel_l[8+h];
    float m = -INFINITY, s = 0.f;
    float acc[8] = {0.f,0.f,0.f,0.f,0.f,0.f,0.f,0.f};

    uint4 raw0 = {0,0,0,0};
    int rel0 = 0;
    if (start < end){
        unsigned p = (unsigned)epk[start];
        int src = p & 0x3FFFFFFF; rel0 = (int)(p >> 30);
        const u16* kb = rel0 ? kr1b : kr0b;
        const u16* vb = rel0 ? vr1b : vr0b;
        const u16* bb = isV ? vb : kb;
        raw0 = *(const uint4*)&bb[(size_t)src*256 + l32*8];
    }
    for (int i = start; i < end; ++i){
        uint4 raw1 = raw0; int rel1 = rel0;
        if (i+1 < end){
            unsigned p = (unsigned)epk[i+1];
            int src = p & 0x3FFFFFFF; rel1 = (int)(p >> 30);
            const u16* kb = rel1 ? kr1b : kr0b;
            const u16* vb = rel1 ? vr1b : vr0b;
            const u16* bb = isV ? vb : kb;
            raw1 = *(const uint4*)&bb[(size_t)src*256 + l32*8];
        }
        float kv[8];
        kv[0]=bf2f(raw0.x&0xffff); kv[1]=bf2f(raw0.x>>16);
        kv[2]=bf2f(raw0.y&0xffff); kv[3]=bf2f(raw0.y>>16);
        kv[4]=bf2f(raw0.z&0xffff); kv[5]=bf2f(raw0.z>>16);
        kv[6]=bf2f(raw0.w&0xffff); kv[7]=bf2f(raw0.w>>16);
        float p = qf[0]*kv[0]+qf[1]*kv[1]+qf[2]*kv[2]+qf[3]*kv[3]
                 +qf[4]*kv[4]+qf[5]*kv[5]+qf[6]*kv[6]+qf[7]*kv[7];
        p += __shfl_xor(p, 1);
        p += __shfl_xor(p, 2);
        p = __shfl(p, l32);
        float logit = p * (rel0 ? p1 : p0) * 0.17677669529663687f;
        float mo = m; m = fmaxf(m, logit);
        float sc = __expf(mo - m);
        float pe = __expf(logit - m);
        s = s*sc + pe;
        #pragma unroll
        for (int j=0;j<8;++j) acc[j] = acc[j]*sc + pe*kv[j];
        raw0 = raw1; rel0 = rel1;
    }
    if (isV){
        float rs = 1.f / fmaxf(s, 1e-16f);
        u16 o[8];
        #pragma unroll
        for (int j=0;j<8;++j) o[j] = f2bf(gelu_exact(acc[j]*rs));
        uint4 ov;
        ov.x = (unsigned)o[0] | ((unsigned)o[1]<<16);
        ov.y = (unsigned)o[2] | ((unsigned)o[3]<<16);
        ov.z = (unsigned)o[4] | ((unsigned)o[5]<<16);
        ov.w = (unsigned)o[6] | ((unsigned)o[7]<<16);
        *(uint4*)&A2[(size_t)node*256 + l32*8] = ov;
    }
}

// ======================= K3: out GEMM (MFMA) + skip blend =======================
// out[r][c] = s*(A2@Wto + bias) + (1-s)*h_in   (pre-LN value, or final output)
__global__ __launch_bounds__(256) void gemmO_k(const u16* __restrict__ A,
        const u16* __restrict__ Wt, const float* __restrict__ bias,
        const float* __restrict__ h_in, const float* __restrict__ skip_l,
        float* __restrict__ outp){
    __shared__ u16 As[4096];
    __shared__ u16 Bs[4096];
    int tid = threadIdx.x;
    int w = tid >> 6, lane = tid & 63;
    int row0 = blockIdx.x * 128;
    int col0 = blockIdx.y * 128;
    int wm = w & 1, wn = w >> 1;
    f32x4 acc[4][4];
    #pragma unroll
    for (int i=0;i<4;++i)
        #pragma unroll
        for (int j=0;j<4;++j) acc[i][j] = (f32x4){0.f,0.f,0.f,0.f};

    int lm = lane & 15, quad = lane >> 4;
    int kq0 = quad ^ (lm & 3);
    int aoff = (wm*64 + lm)*32 + kq0*8;
    int boff = (wn*64 + lm)*32 + kq0*8;

    for (int k0 = 0; k0 < 256; k0 += 32){
        #pragma unroll
        for (int it = 0; it < 2; ++it){
            int s = w*128 + it*64 + lane;
            int row = s >> 2, q0 = s & 3;
            int kq = q0 ^ (row & 3);
            gload_lds16(&A [(size_t)(row0+row)*256 + k0 + kq*8], &As[(size_t)(w*128 + it*64)*8]);
            gload_lds16(&Wt[(size_t)(col0+row)*256 + k0 + kq*8], &Bs[(size_t)(w*128 + it*64)*8]);
        }
        __syncthreads();
        bf16x8 af[4], bfr[4];
        #pragma unroll
        for (int mi=0; mi<4; ++mi) af[mi]  = *(bf16x8*)&As[aoff + mi*512];
        #pragma unroll
        for (int ni=0; ni<4; ++ni) bfr[ni] = *(bf16x8*)&Bs[boff + ni*512];
        #pragma unroll
        for (int mi=0; mi<4; ++mi)
            #pragma unroll
            for (int ni=0; ni<4; ++ni)
                acc[mi][ni] = __builtin_amdgcn_mfma_f32_16x16x32_bf16(af[mi], bfr[ni], acc[mi][ni], 0,0,0);
        __syncthreads();
    }
    float s = 1.f/(1.f+expf(-skip_l[0]));
    float os = 1.f - s;
    #pragma unroll
    for (int ni=0; ni<4; ++ni){
        int colg = col0 + wn*64 + ni*16 + lm;
        float bv = bias[colg];
        #pragma unroll
        for (int mi=0; mi<4; ++mi){
            #pragma unroll
            for (int t=0; t<4; ++t){
                int r = row0 + wm*64 + mi*16 + quad*4 + t;
                if (r < NN)
                    outp[(size_t)r*256 + colg] =
                        s*(acc[mi][ni][t] + bv) + os*h_in[(size_t)r*256 + colg];
            }
        }
    }
}

// ======================= K4: relu + LayerNorm (one wave per row) =======================
__global__ __launch_bounds__(256) void ln_k(const float* __restrict__ hpre,
        const float* __restrict__ g, const float* __restrict__ b,
        float* __restrict__ h_out, u16* __restrict__ hbf){
    int wv = threadIdx.x >> 6, lane = threadIdx.x & 63;
    int row = blockIdx.x*4 + wv;
    float4 v = *(const float4*)&hpre[(size_t)row*256 + lane*4];
    v.x = fmaxf(v.x, 0.f); v.y = fmaxf(v.y, 0.f);
    v.z = fmaxf(v.z, 0.f); v.w = fmaxf(v.w, 0.f);
    float sm = v.x + v.y + v.z + v.w;
    float sq = v.x*v.x + v.y*v.y + v.z*v.z + v.w*v.w;
    #pragma unroll
    for (int d=1; d<64; d<<=1){
        sm += __shfl_xor(sm, d);
        sq += __shfl_xor(sq, d);
    }
    float mu = sm * (1.f/256.f);
    float var = sq * (1.f/256.f) - mu*mu;
    float rstd = rsqrtf(var + 1e-5f);
    float4 gg = *(const float4*)&g[lane*4];
    float4 bb = *(const float4*)&b[lane*4];
    float4 o;
    o.x = (v.x-mu)*rstd*gg.x + bb.x;
    o.y = (v.y-mu)*rstd*gg.y + bb.y;
    o.z = (v.z-mu)*rstd*gg.z + bb.z;
    o.w = (v.w-mu)*rstd*gg.w + bb.w;
    *(float4*)&h_out[(size_t)row*256 + lane*4] = o;
    ushort4 ob = { f2bf(o.x), f2bf(o.y), f2bf(o.z), f2bf(o.w) };
    *(ushort4*)&hbf[(size_t)row*256 + lane*4] = ob;
}

// ======================= host =======================
extern "C" void kernel_launch(void* const* d_in, const int* in_sizes, int n_in,
                              void* d_out, int out_size, void* d_ws, size_t ws_size,
                              hipStream_t stream){
    (void)in_sizes; (void)n_in; (void)out_size; (void)ws_size;
    const float* x     = (const float*)d_in[0];
    const int*   ei0   = (const int*)d_in[1];
    const int*   ei1   = (const int*)d_in[2];
    const float* kqv_w = (const float*)d_in[3];
    const float* kqv_b = (const float*)d_in[4];
    const float* out_w = (const float*)d_in[5];
    const float* out_b = (const float*)d_in[6];
    const float* skip  = (const float*)d_in[7];
    const float* krel  = (const float*)d_in[8];
    const float* vrel  = (const float*)d_in[9];
    const float* prel  = (const float*)d_in[10];
    const float* ln_g  = (const float*)d_in[11];
    const float* ln_b  = (const float*)d_in[12];
    float* outp = (float*)d_out;

    char* wp = (char*)d_ws;
    auto alloc = [&](size_t bytes)->void*{
        void* p = wp; wp += (bytes + 255) & ~(size_t)255; return p;
    };
    float* hA    = (float*)alloc((size_t)NN*CC*4);
    float* hB    = (float*)alloc((size_t)NN*CC*4);
    float* hpre  = (float*)alloc((size_t)NN*CC*4);
    u16*   xbf   = (u16*)alloc((size_t)NPAD*CC*2);
    u16*   hbf   = (u16*)alloc((size_t)NPAD*CC*2);
    u16*   A2    = (u16*)alloc((size_t)NPAD*CC*2);
    u16*   qb    = (u16*)alloc((size_t)NN*CC*2);
    u16*   kr0b  = (u16*)alloc((size_t)NN*CC*2);
    u16*   kr1b  = (u16*)alloc((size_t)NN*CC*2);
    u16*   vr0b  = (u16*)alloc((size_t)NN*CC*2);
    u16*   vr1b  = (u16*)alloc((size_t)NN*CC*2);
    u16*   Wt5   = (u16*)alloc((size_t)4*1280*256*2);
    u16*   Wto   = (u16*)alloc((size_t)4*256*256*2);
    float* bias5 = (float*)alloc((size_t)4*1280*4);
    int* cnt     = (int*)alloc((size_t)NN*4);
    int* incl    = (int*)alloc((size_t)NN*4);
    int* row_ptr = (int*)alloc((size_t)(NN+1)*4);
    int* cursor  = (int*)alloc((size_t)NN*4);
    int* bsum    = (int*)alloc(128*4);
    int* epk     = (int*)alloc((size_t)TE*4);

    // prep (weights + input cast) — independent of CSR chain
    build_w5_k<<<5120,256,0,stream>>>(kqv_w, krel, vrel, Wt5);
    build_bias5_k<<<20,256,0,stream>>>(kqv_b, krel, vrel, bias5);
    build_wo_k<<<1024,256,0,stream>>>(out_w, Wto);
    cvt_x_k<<<2500,256,0,stream>>>(x, xbf);

    // CSR build
    hipMemsetAsync(cnt, 0, (size_t)NN*4, stream);
    hipMemsetAsync(cursor, 0, (size_t)NN*4, stream);
    hist_k<<<1250,256,0,stream>>>(ei0, ei1, cnt);
    scan_block_k<<<79,256,0,stream>>>(cnt, incl, bsum);
    scan_bsum_k<<<1,64,0,stream>>>(bsum, 79);
    finalize_rowptr_k<<<79,256,0,stream>>>(cnt, incl, bsum, row_ptr);
    scatter_k<<<1250,256,0,stream>>>(ei0, ei1, row_ptr, cursor, epk);

    const float* h_in = x;
    const u16*   Ain  = xbf;
    float* houts[4] = {hA, hB, hA, outp};
    for (int l=0; l<4; ++l){
        gemm5_k<<<dim3(157,10),256,0,stream>>>(Ain, Wt5 + (size_t)l*327680,
                bias5 + l*1280, qb, kr0b, kr1b, vr0b, vr1b);
        attn_k<<<5000,256,0,stream>>>(qb, kr0b, kr1b, vr0b, vr1b,
                row_ptr, epk, prel + l*16, A2);
        if (l < 3){
            gemmO_k<<<dim3(157,2),256,0,stream>>>(A2, Wto + (size_t)l*65536,
                    out_b + l*256, h_in, skip + l, hpre);
            ln_k<<<5000,256,0,stream>>>(hpre, ln_g + l*256, ln_b + l*256,
                    houts[l], hbf);
        } else {
            gemmO_k<<<dim3(157,2),256,0,stream>>>(A2, Wto + (size_t)l*65536,
                    out_b + l*256, h_in, skip + l, outp);
        }
        h_in = houts[l];
        Ain = hbf;
    }
}

// Round 5
// 652.835 us; speedup vs baseline: 2.6955x; 1.1579x over previous
//
#include <hip/hip_runtime.h>
#include <math.h>

#define NN 20000
#define NPAD 20096          // padded rows for unguarded MFMA staging
#define CC 256
#define HH 8
#define EE 160000
#define TE 320000

typedef unsigned short u16;
typedef __attribute__((ext_vector_type(8))) short bf16x8;
typedef __attribute__((ext_vector_type(4))) float f32x4;

__device__ __forceinline__ float gelu_exact(float x){
    return 0.5f*x*(1.0f+erff(x*0.7071067811865476f));
}
__device__ __forceinline__ u16 f2bf(float f){
    unsigned u = __float_as_uint(f);
    unsigned r = (u + 0x7fffu + ((u >> 16) & 1u)) >> 16;
    return (u16)r;
}
__device__ __forceinline__ float bf2f(u16 s){
    return __uint_as_float(((unsigned)s) << 16);
}
__device__ __forceinline__ void dec8(uint4 u, float* f){
    f[0]=__uint_as_float(u.x<<16); f[1]=__uint_as_float(u.x&0xffff0000u);
    f[2]=__uint_as_float(u.y<<16); f[3]=__uint_as_float(u.y&0xffff0000u);
    f[4]=__uint_as_float(u.z<<16); f[5]=__uint_as_float(u.z&0xffff0000u);
    f[6]=__uint_as_float(u.w<<16); f[7]=__uint_as_float(u.w&0xffff0000u);
}
__device__ __forceinline__ void gload_lds16(const u16* gsrc, u16* lds_dst){
    __builtin_amdgcn_global_load_lds((const __attribute__((address_space(1))) unsigned int*)gsrc,
                                     (__attribute__((address_space(3))) unsigned int*)lds_dst,
                                     16, 0, 0);
}

// ======================= CSR build =======================
__global__ void hist_k(const int* __restrict__ ei0, const int* __restrict__ ei1,
                       int* __restrict__ cnt){
    int e = blockIdx.x*256 + threadIdx.x;
    if (e < TE){
        int dst = (e < EE) ? ei0[EE + e] : ei1[EE + (e - EE)];
        atomicAdd(&cnt[dst], 1);
    }
}
__global__ void scan_block_k(const int* __restrict__ cnt, int* __restrict__ incl,
                             int* __restrict__ bsum){
    __shared__ int tmp[256];
    int tid = threadIdx.x;
    int i = blockIdx.x*256 + tid;
    int v = (i < NN) ? cnt[i] : 0;
    tmp[tid] = v;
    __syncthreads();
    for (int d=1; d<256; d<<=1){
        int t = (tid>=d) ? tmp[tid-d] : 0;
        __syncthreads();
        tmp[tid] += t;
        __syncthreads();
    }
    if (i < NN) incl[i] = tmp[tid];
    if (tid == 255) bsum[blockIdx.x] = tmp[255];
}
// parallel exclusive scan of <=128 block sums (replaces 1-thread serial loop)
__global__ void scan_bsum_k(int* bsum, int nb){
    __shared__ int tmp[128];
    int tid = threadIdx.x;
    int v = (tid < nb) ? bsum[tid] : 0;
    tmp[tid] = v;
    __syncthreads();
    for (int d=1; d<128; d<<=1){
        int t = (tid>=d) ? tmp[tid-d] : 0;
        __syncthreads();
        tmp[tid] += t;
        __syncthreads();
    }
    if (tid < nb) bsum[tid] = tmp[tid] - v;   // exclusive
}
__global__ void finalize_rowptr_k(const int* __restrict__ cnt, const int* __restrict__ incl,
                                  const int* __restrict__ bsum, int* __restrict__ row_ptr){
    int i = blockIdx.x*256 + threadIdx.x;
    if (i < NN) row_ptr[i] = incl[i] - cnt[i] + bsum[blockIdx.x];
    if (i == NN) row_ptr[NN] = TE;
}
// packs src | rel<<30 per CSR slot
__global__ void scatter_k(const int* __restrict__ ei0, const int* __restrict__ ei1,
                          const int* __restrict__ row_ptr, int* __restrict__ cursor,
                          int* __restrict__ epk){
    int e = blockIdx.x*256 + threadIdx.x;
    if (e < TE){
        int src, dst, rel;
        if (e < EE){ src = ei0[e]; dst = ei0[EE+e]; rel = 0; }
        else { int ee=e-EE; src = ei1[ee]; dst = ei1[EE+ee]; rel = 1; }
        int pos = atomicAdd(&cursor[dst], 1);
        epk[row_ptr[dst] + pos] = src | (rel << 30);
    }
}

// ======================= weight prep =======================
__global__ void build_w5_k(const float* __restrict__ kqv_w, const float* __restrict__ krel,
                           const float* __restrict__ vrel, u16* __restrict__ Wt){
    int idx = blockIdx.x*256 + threadIdx.x;        // 4*1280*256
    int k = idx & 255;
    int n = (idx >> 8) % 1280;
    int l = idx / (1280*256);
    const float* W = kqv_w + (size_t)l*196608;     // [256][768]
    float val;
    if (n < 256){
        val = W[k*768 + 256 + n];
    } else {
        int g = (n-256) >> 8;
        int r = g & 1, isv = g >> 1;
        int c = (n-256) & 255;
        int h = c >> 5, f = c & 31;
        const float* Rm = (isv ? vrel : krel) + ((size_t)l*2 + r)*8192 + h*1024; // [32][32]
        int base = isv ? 512 : 0;
        float a = 0.f;
        #pragma unroll 8
        for (int d=0; d<32; ++d)
            a += W[k*768 + base + h*32 + d] * Rm[d*32 + f];
        val = a;
    }
    Wt[(size_t)l*327680 + (size_t)n*256 + k] = f2bf(val);
}
__global__ void build_bias5_k(const float* __restrict__ kqv_b, const float* __restrict__ krel,
                              const float* __restrict__ vrel, float* __restrict__ bias5){
    int idx = blockIdx.x*256 + threadIdx.x;        // 4*1280
    if (idx >= 4*1280) return;
    int n = idx % 1280, l = idx / 1280;
    const float* B = kqv_b + l*768;
    float val;
    if (n < 256) val = B[256+n];
    else {
        int g = (n-256) >> 8;
        int r = g & 1, isv = g >> 1;
        int c = (n-256) & 255;
        int h = c >> 5, f = c & 31;
        const float* Rm = (isv ? vrel : krel) + ((size_t)l*2 + r)*8192 + h*1024;
        int base = isv ? 512 : 0;
        float a = 0.f;
        for (int d=0; d<32; ++d) a += B[base + h*32 + d] * Rm[d*32 + f];
        val = a;
    }
    bias5[idx] = val;
}
// transpose out_w [l][k][n] fp32 -> Wto [l][n][k] bf16
__global__ void build_wo_k(const float* __restrict__ out_w, u16* __restrict__ Wto){
    int idx = blockIdx.x*256 + threadIdx.x;        // 4*256*256
    int k = idx & 255;
    int n = (idx >> 8) & 255;
    int l = idx >> 16;
    Wto[(size_t)l*65536 + n*256 + k] = f2bf(out_w[(size_t)l*65536 + k*256 + n]);
}
__global__ void cvt_x_k(const float* __restrict__ x, u16* __restrict__ xbf){
    int idx = blockIdx.x*256 + threadIdx.x;        // 640000 (8 elems each)
    const float4* xp = (const float4*)x;
    float4 a = xp[(size_t)idx*2], b = xp[(size_t)idx*2+1];
    uint4 o;
    o.x = (unsigned)f2bf(a.x) | ((unsigned)f2bf(a.y)<<16);
    o.y = (unsigned)f2bf(a.z) | ((unsigned)f2bf(a.w)<<16);
    o.z = (unsigned)f2bf(b.x) | ((unsigned)f2bf(b.y)<<16);
    o.w = (unsigned)f2bf(b.z) | ((unsigned)f2bf(b.w)<<16);
    *(uint4*)&xbf[(size_t)idx*8] = o;
}

// ======================= K1: 5-output MFMA GEMM =======================
__global__ __launch_bounds__(256) void gemm5_k(const u16* __restrict__ A,
        const u16* __restrict__ Wt, const float* __restrict__ biasp,
        u16* __restrict__ qb, u16* __restrict__ kr0b, u16* __restrict__ kr1b,
        u16* __restrict__ vr0b, u16* __restrict__ vr1b){
    __shared__ u16 As[4096];   // 128 rows x 32 k (16B slots, XOR-swizzled)
    __shared__ u16 Bs[4096];
    int tid = threadIdx.x;
    int w = tid >> 6, lane = tid & 63;
    int row0 = blockIdx.x * 128;
    int col0 = blockIdx.y * 128;
    int wm = w & 1, wn = w >> 1;
    f32x4 acc[4][4];
    #pragma unroll
    for (int i=0;i<4;++i)
        #pragma unroll
        for (int j=0;j<4;++j) acc[i][j] = (f32x4){0.f,0.f,0.f,0.f};

    int lm = lane & 15, quad = lane >> 4;
    int kq0 = quad ^ (lm & 3);
    int aoff = (wm*64 + lm)*32 + kq0*8;
    int boff = (wn*64 + lm)*32 + kq0*8;

    for (int k0 = 0; k0 < 256; k0 += 32){
        #pragma unroll
        for (int it = 0; it < 2; ++it){
            int s = w*128 + it*64 + lane;      // 16B slot id
            int row = s >> 2, q0 = s & 3;
            int kq = q0 ^ (row & 3);
            gload_lds16(&A [(size_t)(row0+row)*256 + k0 + kq*8], &As[(size_t)(w*128 + it*64)*8]);
            gload_lds16(&Wt[(size_t)(col0+row)*256 + k0 + kq*8], &Bs[(size_t)(w*128 + it*64)*8]);
        }
        __syncthreads();
        bf16x8 af[4], bfr[4];
        #pragma unroll
        for (int mi=0; mi<4; ++mi) af[mi]  = *(bf16x8*)&As[aoff + mi*512];
        #pragma unroll
        for (int ni=0; ni<4; ++ni) bfr[ni] = *(bf16x8*)&Bs[boff + ni*512];
        #pragma unroll
        for (int mi=0; mi<4; ++mi)
            #pragma unroll
            for (int ni=0; ni<4; ++ni)
                acc[mi][ni] = __builtin_amdgcn_mfma_f32_16x16x32_bf16(af[mi], bfr[ni], acc[mi][ni], 0,0,0);
        __syncthreads();
    }
    int bufi = col0 >> 8;
    u16* obuf = (bufi==0)?qb:((bufi==1)?kr0b:((bufi==2)?kr1b:((bufi==3)?vr0b:vr1b)));
    #pragma unroll
    for (int ni=0; ni<4; ++ni){
        int colg = col0 + wn*64 + ni*16 + lm;
        float bv = biasp[colg];
        int cw = colg & 255;
        #pragma unroll
        for (int mi=0; mi<4; ++mi){
            #pragma unroll
            for (int t=0; t<4; ++t){
                int r = row0 + wm*64 + mi*16 + quad*4 + t;
                if (r < NN) obuf[(size_t)r*256 + cw] = f2bf(acc[mi][ni][t] + bv);
            }
        }
    }
}

// ======================= K2: split-wave CSR attention, online softmax ==============
// one wave per node; each 32-lane half processes alternate edges (even/odd),
// doing the FULL per-edge work (k-dot AND v-accumulate) -> 2x useful VALU density.
// States merged across halves at the end via shfl_xor(.,32).
__global__ __launch_bounds__(256) void attn_k(const u16* __restrict__ qb,
        const u16* __restrict__ kr0b, const u16* __restrict__ kr1b,
        const u16* __restrict__ vr0b, const u16* __restrict__ vr1b,
        const int* __restrict__ row_ptr, const int* __restrict__ epk,
        const float* __restrict__ prel_l, u16* __restrict__ A2){
    int wv = threadIdx.x >> 6, lane = threadIdx.x & 63;
    int node = blockIdx.x*4 + wv;
    int l32 = lane & 31;
    int half = lane >> 5;
    int start = row_ptr[node], end = row_ptr[node+1];
    float qf[8];
    {
        uint4 qr = *(const uint4*)&qb[(size_t)node*256 + l32*8];
        dec8(qr, qf);
    }
    int h = l32 >> 2;
    float pr0 = prel_l[h]     * 0.17677669529663687f;   // /sqrt(32)
    float pr1 = prel_l[8 + h] * 0.17677669529663687f;
    float m = -INFINITY, s = 0.f;
    float acc[8] = {0.f,0.f,0.f,0.f,0.f,0.f,0.f,0.f};

    uint4 kraw = {0,0,0,0}, vraw = {0,0,0,0};
    float pscale = 0.f;
    int i0 = start + half;
    if (i0 < end){
        unsigned p = (unsigned)epk[i0];
        int src = p & 0x3FFFFFFF; unsigned rel = p >> 30;
        const u16* kb = rel ? kr1b : kr0b;
        const u16* vb = rel ? vr1b : vr0b;
        kraw = *(const uint4*)&kb[(size_t)src*256 + l32*8];
        vraw = *(const uint4*)&vb[(size_t)src*256 + l32*8];
        pscale = rel ? pr1 : pr0;
    }
    for (int i = i0; i < end; i += 2){
        uint4 kc = kraw, vc = vraw;
        float psc = pscale;
        if (i + 2 < end){                      // prefetch next edge of this half
            unsigned p = (unsigned)epk[i+2];
            int src = p & 0x3FFFFFFF; unsigned rel = p >> 30;
            const u16* kb = rel ? kr1b : kr0b;
            const u16* vb = rel ? vr1b : vr0b;
            kraw = *(const uint4*)&kb[(size_t)src*256 + l32*8];
            vraw = *(const uint4*)&vb[(size_t)src*256 + l32*8];
            pscale = rel ? pr1 : pr0;
        }
        float kv[8];
        dec8(kc, kv);
        float p = qf[0]*kv[0]+qf[1]*kv[1]+qf[2]*kv[2]+qf[3]*kv[3]
                 +qf[4]*kv[4]+qf[5]*kv[5]+qf[6]*kv[6]+qf[7]*kv[7];
        p += __shfl_xor(p, 1);
        p += __shfl_xor(p, 2);                 // 4-lane head-group reduce (stays in half)
        float logit = p * psc;
        float mo = m;
        m = fmaxf(m, logit);
        float sc = __expf(mo - m);             // first edge: exp(-inf)=0
        float pe = __expf(logit - m);
        s = s*sc + pe;
        float vv[8];
        dec8(vc, vv);
        #pragma unroll
        for (int j=0;j<8;++j) acc[j] = acc[j]*sc + pe*vv[j];
    }
    // merge the two halves' online-softmax states
    float mO = __shfl_xor(m, 32);
    float mA = fmaxf(m, mO);
    if (mA == -INFINITY) mA = 0.f;             // empty node guard (avoid inf-inf NaN)
    float eS = __expf(m - mA);
    float sh = s * eS;
    float sA = sh + __shfl_xor(sh, 32);
    float rs = 1.f / fmaxf(sA, 1e-16f);
    float oA[8];
    #pragma unroll
    for (int j=0;j<8;++j){
        float a = acc[j] * eS;
        oA[j] = a + __shfl_xor(a, 32);
    }
    if (half == 0){
        u16 o[8];
        #pragma unroll
        for (int j=0;j<8;++j) o[j] = f2bf(gelu_exact(oA[j]*rs));
        uint4 ov;
        ov.x = (unsigned)o[0] | ((unsigned)o[1]<<16);
        ov.y = (unsigned)o[2] | ((unsigned)o[3]<<16);
        ov.z = (unsigned)o[4] | ((unsigned)o[5]<<16);
        ov.w = (unsigned)o[6] | ((unsigned)o[7]<<16);
        *(uint4*)&A2[(size_t)node*256 + l32*8] = ov;
    }
}

// ======================= K3a: out GEMM + skip + relu + LN (layers 0-2) ===========
// 64-row x 256-col block tile: full rows in-block -> LN fused.
__global__ __launch_bounds__(256) void gemmOln_k(const u16* __restrict__ A,
        const u16* __restrict__ Wt, const float* __restrict__ bias,
        const float* __restrict__ h_in, const float* __restrict__ skip_l,
        const float* __restrict__ g, const float* __restrict__ b,
        float* __restrict__ h_out, u16* __restrict__ hbf){
    __shared__ u16 As[2048];          // 64 rows x 32 k
    __shared__ u16 Bs[8192];          // 256 cols x 32 k
    __shared__ float part_s[64*33];   // stride 33: breaks quad-bank aliasing
    __shared__ float part_q[64*33];
    __shared__ float mu_s[64], rstd_s[64];
    int tid = threadIdx.x;
    int w = tid >> 6, lane = tid & 63;
    int row0 = blockIdx.x * 64;
    int wm = w & 1, wn = w >> 1;      // wave tile: 32 rows x 128 cols
    f32x4 acc[2][8];
    #pragma unroll
    for (int i=0;i<2;++i)
        #pragma unroll
        for (int j=0;j<8;++j) acc[i][j] = (f32x4){0.f,0.f,0.f,0.f};

    int lm = lane & 15, quad = lane >> 4;
    int kq0 = quad ^ (lm & 3);
    int aoff = (wm*32 + lm)*32 + kq0*8;
    int boff = (wn*128 + lm)*32 + kq0*8;

    for (int k0 = 0; k0 < 256; k0 += 32){
        {   // A: 256 slots (one per thread)
            int s = tid;
            int row = s >> 2, q0 = s & 3;
            int kq = q0 ^ (row & 3);
            gload_lds16(&A[(size_t)(row0+row)*256 + k0 + kq*8], &As[(size_t)(w*64)*8]);
        }
        #pragma unroll
        for (int it = 0; it < 4; ++it){   // B: 1024 slots
            int s = it*256 + w*64 + lane;
            int row = s >> 2, q0 = s & 3;
            int kq = q0 ^ (row & 3);
            gload_lds16(&Wt[(size_t)row*256 + k0 + kq*8], &Bs[(size_t)(it*256 + w*64)*8]);
        }
        __syncthreads();
        bf16x8 af[2], bfr[8];
        #pragma unroll
        for (int mi=0; mi<2; ++mi) af[mi]  = *(bf16x8*)&As[aoff + mi*512];
        #pragma unroll
        for (int ni=0; ni<8; ++ni) bfr[ni] = *(bf16x8*)&Bs[boff + ni*512];
        #pragma unroll
        for (int mi=0; mi<2; ++mi)
            #pragma unroll
            for (int ni=0; ni<8; ++ni)
                acc[mi][ni] = __builtin_amdgcn_mfma_f32_16x16x32_bf16(af[mi], bfr[ni], acc[mi][ni], 0,0,0);
        __syncthreads();
    }

    float sskip = 1.f/(1.f+__expf(-skip_l[0]));
    float osk = 1.f - sskip;
    float bv[8], gv[8], bbv[8];
    #pragma unroll
    for (int ni=0; ni<8; ++ni){
        int colg = wn*128 + ni*16 + lm;
        bv[ni]  = bias[colg];
        gv[ni]  = g[colg];
        bbv[ni] = b[colg];
    }
    // blend + relu, accumulate row partials
    #pragma unroll
    for (int mi=0; mi<2; ++mi){
        #pragma unroll
        for (int t=0; t<4; ++t){
            int lr = wm*32 + mi*16 + quad*4 + t;
            int r = row0 + lr;
            float ps = 0.f, pq = 0.f;
            #pragma unroll
            for (int ni=0; ni<8; ++ni){
                int colg = wn*128 + ni*16 + lm;
                float hv = (r < NN) ? h_in[(size_t)r*256 + colg] : 0.f;
                float val = sskip*(acc[mi][ni][t] + bv[ni]) + osk*hv;
                val = fmaxf(val, 0.f);
                acc[mi][ni][t] = val;
                ps += val; pq += val*val;
            }
            part_s[lr*33 + wn*16 + lm] = ps;
            part_q[lr*33 + wn*16 + lm] = pq;
        }
    }
    __syncthreads();
    if (tid < 64){
        float S = 0.f, Q = 0.f;
        #pragma unroll 8
        for (int t2=0; t2<32; ++t2){
            S += part_s[tid*33 + t2];
            Q += part_q[tid*33 + t2];
        }
        float mu = S * (1.f/256.f);
        float var = Q * (1.f/256.f) - mu*mu;
        mu_s[tid] = mu;
        rstd_s[tid] = rsqrtf(var + 1e-5f);
    }
    __syncthreads();
    #pragma unroll
    for (int mi=0; mi<2; ++mi){
        #pragma unroll
        for (int t=0; t<4; ++t){
            int lr = wm*32 + mi*16 + quad*4 + t;
            int r = row0 + lr;
            if (r >= NN) continue;
            float mu = mu_s[lr], rstd = rstd_s[lr];
            #pragma unroll
            for (int ni=0; ni<8; ++ni){
                int colg = wn*128 + ni*16 + lm;
                float o = (acc[mi][ni][t] - mu)*rstd*gv[ni] + bbv[ni];
                h_out[(size_t)r*256 + colg] = o;
                hbf[(size_t)r*256 + colg] = f2bf(o);
            }
        }
    }
}

// ======================= K3b: out GEMM + skip blend (final layer) =======================
__global__ __launch_bounds__(256) void gemmO_k(const u16* __restrict__ A,
        const u16* __restrict__ Wt, const float* __restrict__ bias,
        const float* __restrict__ h_in, const float* __restrict__ skip_l,
        float* __restrict__ outp){
    __shared__ u16 As[4096];
    __shared__ u16 Bs[4096];
    int tid = threadIdx.x;
    int w = tid >> 6, lane = tid & 63;
    int row0 = blockIdx.x * 128;
    int col0 = blockIdx.y * 128;
    int wm = w & 1, wn = w >> 1;
    f32x4 acc[4][4];
    #pragma unroll
    for (int i=0;i<4;++i)
        #pragma unroll
        for (int j=0;j<4;++j) acc[i][j] = (f32x4){0.f,0.f,0.f,0.f};

    int lm = lane & 15, quad = lane >> 4;
    int kq0 = quad ^ (lm & 3);
    int aoff = (wm*64 + lm)*32 + kq0*8;
    int boff = (wn*64 + lm)*32 + kq0*8;

    for (int k0 = 0; k0 < 256; k0 += 32){
        #pragma unroll
        for (int it = 0; it < 2; ++it){
            int s = w*128 + it*64 + lane;
            int row = s >> 2, q0 = s & 3;
            int kq = q0 ^ (row & 3);
            gload_lds16(&A [(size_t)(row0+row)*256 + k0 + kq*8], &As[(size_t)(w*128 + it*64)*8]);
            gload_lds16(&Wt[(size_t)(col0+row)*256 + k0 + kq*8], &Bs[(size_t)(w*128 + it*64)*8]);
        }
        __syncthreads();
        bf16x8 af[4], bfr[4];
        #pragma unroll
        for (int mi=0; mi<4; ++mi) af[mi]  = *(bf16x8*)&As[aoff + mi*512];
        #pragma unroll
        for (int ni=0; ni<4; ++ni) bfr[ni] = *(bf16x8*)&Bs[boff + ni*512];
        #pragma unroll
        for (int mi=0; mi<4; ++mi)
            #pragma unroll
            for (int ni=0; ni<4; ++ni)
                acc[mi][ni] = __builtin_amdgcn_mfma_f32_16x16x32_bf16(af[mi], bfr[ni], acc[mi][ni], 0,0,0);
        __syncthreads();
    }
    float s = 1.f/(1.f+expf(-skip_l[0]));
    float os = 1.f - s;
    #pragma unroll
    for (int ni=0; ni<4; ++ni){
        int colg = col0 + wn*64 + ni*16 + lm;
        float bv = bias[colg];
        #pragma unroll
        for (int mi=0; mi<4; ++mi){
            #pragma unroll
            for (int t=0; t<4; ++t){
                int r = row0 + wm*64 + mi*16 + quad*4 + t;
                if (r < NN)
                    outp[(size_t)r*256 + colg] =
                        s*(acc[mi][ni][t] + bv) + os*h_in[(size_t)r*256 + colg];
            }
        }
    }
}

// ======================= host =======================
extern "C" void kernel_launch(void* const* d_in, const int* in_sizes, int n_in,
                              void* d_out, int out_size, void* d_ws, size_t ws_size,
                              hipStream_t stream){
    (void)in_sizes; (void)n_in; (void)out_size; (void)ws_size;
    const float* x     = (const float*)d_in[0];
    const int*   ei0   = (const int*)d_in[1];
    const int*   ei1   = (const int*)d_in[2];
    const float* kqv_w = (const float*)d_in[3];
    const float* kqv_b = (const float*)d_in[4];
    const float* out_w = (const float*)d_in[5];
    const float* out_b = (const float*)d_in[6];
    const float* skip  = (const float*)d_in[7];
    const float* krel  = (const float*)d_in[8];
    const float* vrel  = (const float*)d_in[9];
    const float* prel  = (const float*)d_in[10];
    const float* ln_g  = (const float*)d_in[11];
    const float* ln_b  = (const float*)d_in[12];
    float* outp = (float*)d_out;

    char* wp = (char*)d_ws;
    auto alloc = [&](size_t bytes)->void*{
        void* p = wp; wp += (bytes + 255) & ~(size_t)255; return p;
    };
    float* hA    = (float*)alloc((size_t)NN*CC*4);
    float* hB    = (float*)alloc((size_t)NN*CC*4);
    u16*   xbf   = (u16*)alloc((size_t)NPAD*CC*2);
    u16*   hbf   = (u16*)alloc((size_t)NPAD*CC*2);
    u16*   A2    = (u16*)alloc((size_t)NPAD*CC*2);
    u16*   qb    = (u16*)alloc((size_t)NN*CC*2);
    u16*   kr0b  = (u16*)alloc((size_t)NN*CC*2);
    u16*   kr1b  = (u16*)alloc((size_t)NN*CC*2);
    u16*   vr0b  = (u16*)alloc((size_t)NN*CC*2);
    u16*   vr1b  = (u16*)alloc((size_t)NN*CC*2);
    u16*   Wt5   = (u16*)alloc((size_t)4*1280*256*2);
    u16*   Wto   = (u16*)alloc((size_t)4*256*256*2);
    float* bias5 = (float*)alloc((size_t)4*1280*4);
    int* cnt     = (int*)alloc((size_t)NN*4);      // cnt+cursor adjacent: one memset
    int* cursor  = (int*)alloc((size_t)NN*4);
    int* incl    = (int*)alloc((size_t)NN*4);
    int* row_ptr = (int*)alloc((size_t)(NN+1)*4);
    int* bsum    = (int*)alloc(128*4);
    int* epk     = (int*)alloc((size_t)TE*4);

    // prep (weights + input cast) — independent of CSR chain
    build_w5_k<<<5120,256,0,stream>>>(kqv_w, krel, vrel, Wt5);
    build_bias5_k<<<20,256,0,stream>>>(kqv_b, krel, vrel, bias5);
    build_wo_k<<<1024,256,0,stream>>>(out_w, Wto);
    cvt_x_k<<<2500,256,0,stream>>>(x, xbf);

    // CSR build
    size_t cntBlk = ((size_t)NN*4 + 255) & ~(size_t)255;
    hipMemsetAsync(cnt, 0, cntBlk + (size_t)NN*4, stream);   // zero cnt AND cursor
    hist_k<<<1250,256,0,stream>>>(ei0, ei1, cnt);
    scan_block_k<<<79,256,0,stream>>>(cnt, incl, bsum);
    scan_bsum_k<<<1,128,0,stream>>>(bsum, 79);
    finalize_rowptr_k<<<79,256,0,stream>>>(cnt, incl, bsum, row_ptr);
    scatter_k<<<1250,256,0,stream>>>(ei0, ei1, row_ptr, cursor, epk);

    const float* h_in = x;
    const u16*   Ain  = xbf;
    float* houts[4] = {hA, hB, hA, outp};
    for (int l=0; l<4; ++l){
        gemm5_k<<<dim3(157,10),256,0,stream>>>(Ain, Wt5 + (size_t)l*327680,
                bias5 + l*1280, qb, kr0b, kr1b, vr0b, vr1b);
        attn_k<<<5000,256,0,stream>>>(qb, kr0b, kr1b, vr0b, vr1b,
                row_ptr, epk, prel + l*16, A2);
        if (l < 3){
            gemmOln_k<<<314,256,0,stream>>>(A2, Wto + (size_t)l*65536,
                    out_b + l*256, h_in, skip + l, ln_g + l*256, ln_b + l*256,
                    houts[l], hbf);
        } else {
            gemmO_k<<<dim3(157,2),256,0,stream>>>(A2, Wto + (size_t)l*65536,
                    out_b + l*256, h_in, skip + l, outp);
        }
        h_in = houts[l];
        Ain = hbf;
    }
}

// Round 6
// 609.944 us; speedup vs baseline: 2.8850x; 1.0703x over previous
//
#include <hip/hip_runtime.h>
#include <math.h>

#define NN 20000
#define NPAD 20096          // padded rows for unguarded MFMA staging
#define CC 256
#define HH 8
#define EE 160000
#define TE 320000

typedef unsigned short u16;
typedef __attribute__((ext_vector_type(8))) short bf16x8;
typedef __attribute__((ext_vector_type(4))) float f32x4;

__device__ __forceinline__ float gelu_exact(float x){
    return 0.5f*x*(1.0f+erff(x*0.7071067811865476f));
}
__device__ __forceinline__ u16 f2bf(float f){
    unsigned u = __float_as_uint(f);
    unsigned r = (u + 0x7fffu + ((u >> 16) & 1u)) >> 16;
    return (u16)r;
}
__device__ __forceinline__ float bf2f(u16 s){
    return __uint_as_float(((unsigned)s) << 16);
}
__device__ __forceinline__ void dec8(uint4 u, float* f){
    f[0]=__uint_as_float(u.x<<16); f[1]=__uint_as_float(u.x&0xffff0000u);
    f[2]=__uint_as_float(u.y<<16); f[3]=__uint_as_float(u.y&0xffff0000u);
    f[4]=__uint_as_float(u.z<<16); f[5]=__uint_as_float(u.z&0xffff0000u);
    f[6]=__uint_as_float(u.w<<16); f[7]=__uint_as_float(u.w&0xffff0000u);
}
__device__ __forceinline__ void gload_lds16(const u16* gsrc, u16* lds_dst){
    __builtin_amdgcn_global_load_lds((const __attribute__((address_space(1))) unsigned int*)gsrc,
                                     (__attribute__((address_space(3))) unsigned int*)lds_dst,
                                     16, 0, 0);
}

// ======================= CSR build =======================
__global__ void hist_k(const int* __restrict__ ei0, const int* __restrict__ ei1,
                       int* __restrict__ cnt){
    int e = blockIdx.x*256 + threadIdx.x;
    if (e < TE){
        int dst = (e < EE) ? ei0[EE + e] : ei1[EE + (e - EE)];
        atomicAdd(&cnt[dst], 1);
    }
}
__global__ void scan_block_k(const int* __restrict__ cnt, int* __restrict__ incl,
                             int* __restrict__ bsum){
    __shared__ int tmp[256];
    int tid = threadIdx.x;
    int i = blockIdx.x*256 + tid;
    int v = (i < NN) ? cnt[i] : 0;
    tmp[tid] = v;
    __syncthreads();
    for (int d=1; d<256; d<<=1){
        int t = (tid>=d) ? tmp[tid-d] : 0;
        __syncthreads();
        tmp[tid] += t;
        __syncthreads();
    }
    if (i < NN) incl[i] = tmp[tid];
    if (tid == 255) bsum[blockIdx.x] = tmp[255];
}
__global__ void scan_bsum_k(int* bsum, int nb){
    __shared__ int tmp[128];
    int tid = threadIdx.x;
    int v = (tid < nb) ? bsum[tid] : 0;
    tmp[tid] = v;
    __syncthreads();
    for (int d=1; d<128; d<<=1){
        int t = (tid>=d) ? tmp[tid-d] : 0;
        __syncthreads();
        tmp[tid] += t;
        __syncthreads();
    }
    if (tid < nb) bsum[tid] = tmp[tid] - v;   // exclusive
}
__global__ void finalize_rowptr_k(const int* __restrict__ cnt, const int* __restrict__ incl,
                                  const int* __restrict__ bsum, int* __restrict__ row_ptr){
    int i = blockIdx.x*256 + threadIdx.x;
    if (i < NN) row_ptr[i] = incl[i] - cnt[i] + bsum[blockIdx.x];
    if (i == NN) row_ptr[NN] = TE;
}
__global__ void scatter_k(const int* __restrict__ ei0, const int* __restrict__ ei1,
                          const int* __restrict__ row_ptr, int* __restrict__ cursor,
                          int* __restrict__ epk){
    int e = blockIdx.x*256 + threadIdx.x;
    if (e < TE){
        int src, dst, rel;
        if (e < EE){ src = ei0[e]; dst = ei0[EE+e]; rel = 0; }
        else { int ee=e-EE; src = ei1[ee]; dst = ei1[EE+ee]; rel = 1; }
        int pos = atomicAdd(&cursor[dst], 1);
        epk[row_ptr[dst] + pos] = src | (rel << 30);
    }
}

// ======================= weight prep =======================
__global__ void build_w5_k(const float* __restrict__ kqv_w, const float* __restrict__ krel,
                           const float* __restrict__ vrel, u16* __restrict__ Wt){
    int idx = blockIdx.x*256 + threadIdx.x;        // 4*1280*256
    int k = idx & 255;
    int n = (idx >> 8) % 1280;
    int l = idx / (1280*256);
    const float* W = kqv_w + (size_t)l*196608;     // [256][768]
    float val;
    if (n < 256){
        val = W[k*768 + 256 + n];
    } else {
        int g = (n-256) >> 8;
        int r = g & 1, isv = g >> 1;
        int c = (n-256) & 255;
        int h = c >> 5, f = c & 31;
        const float* Rm = (isv ? vrel : krel) + ((size_t)l*2 + r)*8192 + h*1024; // [32][32]
        int base = isv ? 512 : 0;
        float a = 0.f;
        #pragma unroll 8
        for (int d=0; d<32; ++d)
            a += W[k*768 + base + h*32 + d] * Rm[d*32 + f];
        val = a;
    }
    Wt[(size_t)l*327680 + (size_t)n*256 + k] = f2bf(val);
}
__global__ void build_bias5_k(const float* __restrict__ kqv_b, const float* __restrict__ krel,
                              const float* __restrict__ vrel, float* __restrict__ bias5){
    int idx = blockIdx.x*256 + threadIdx.x;        // 4*1280
    if (idx >= 4*1280) return;
    int n = idx % 1280, l = idx / 1280;
    const float* B = kqv_b + l*768;
    float val;
    if (n < 256) val = B[256+n];
    else {
        int g = (n-256) >> 8;
        int r = g & 1, isv = g >> 1;
        int c = (n-256) & 255;
        int h = c >> 5, f = c & 31;
        const float* Rm = (isv ? vrel : krel) + ((size_t)l*2 + r)*8192 + h*1024;
        int base = isv ? 512 : 0;
        float a = 0.f;
        for (int d=0; d<32; ++d) a += B[base + h*32 + d] * Rm[d*32 + f];
        val = a;
    }
    bias5[idx] = val;
}
// transpose out_w [l][k][n] fp32 -> Wto [l][n][k] bf16
__global__ void build_wo_k(const float* __restrict__ out_w, u16* __restrict__ Wto){
    int idx = blockIdx.x*256 + threadIdx.x;        // 4*256*256
    int k = idx & 255;
    int n = (idx >> 8) & 255;
    int l = idx >> 16;
    Wto[(size_t)l*65536 + n*256 + k] = f2bf(out_w[(size_t)l*65536 + k*256 + n]);
}
__global__ void cvt_x_k(const float* __restrict__ x, u16* __restrict__ xbf){
    int idx = blockIdx.x*256 + threadIdx.x;        // 640000 (8 elems each)
    const float4* xp = (const float4*)x;
    float4 a = xp[(size_t)idx*2], b = xp[(size_t)idx*2+1];
    uint4 o;
    o.x = (unsigned)f2bf(a.x) | ((unsigned)f2bf(a.y)<<16);
    o.y = (unsigned)f2bf(a.z) | ((unsigned)f2bf(a.w)<<16);
    o.z = (unsigned)f2bf(b.x) | ((unsigned)f2bf(b.y)<<16);
    o.w = (unsigned)f2bf(b.z) | ((unsigned)f2bf(b.w)<<16);
    *(uint4*)&xbf[(size_t)idx*8] = o;
}

// ======================= K1: 5-output MFMA GEMM =======================
// grid (10, 157): col-tile fastest -> consecutive blocks reuse the A row-tile.
// Epilogue: LDS transpose (f32) -> fully-vectorized 16B bf16 stores.
__global__ __launch_bounds__(256) void gemm5_k(const u16* __restrict__ A,
        const u16* __restrict__ Wt, const float* __restrict__ biasp,
        u16* __restrict__ qb, u16* __restrict__ kr0b, u16* __restrict__ kr1b,
        u16* __restrict__ vr0b, u16* __restrict__ vr1b){
    __shared__ u16 As[4096];   // 128 rows x 32 k (16B slots, XOR-swizzled)
    __shared__ u16 Bs[4096];
    __shared__ float Cs[128*66];   // 64-col chunk, stride 66 (+2 pad)
    int tid = threadIdx.x;
    int w = tid >> 6, lane = tid & 63;
    int col0 = blockIdx.x * 128;
    int row0 = blockIdx.y * 128;
    int wm = w & 1, wn = w >> 1;
    f32x4 acc[4][4];
    #pragma unroll
    for (int i=0;i<4;++i)
        #pragma unroll
        for (int j=0;j<4;++j) acc[i][j] = (f32x4){0.f,0.f,0.f,0.f};

    int lm = lane & 15, quad = lane >> 4;
    int kq0 = quad ^ (lm & 3);
    int aoff = (wm*64 + lm)*32 + kq0*8;
    int boff = (wn*64 + lm)*32 + kq0*8;

    for (int k0 = 0; k0 < 256; k0 += 32){
        #pragma unroll
        for (int it = 0; it < 2; ++it){
            int s = w*128 + it*64 + lane;      // 16B slot id
            int row = s >> 2, q0 = s & 3;
            int kq = q0 ^ (row & 3);
            gload_lds16(&A [(size_t)(row0+row)*256 + k0 + kq*8], &As[(size_t)(w*128 + it*64)*8]);
            gload_lds16(&Wt[(size_t)(col0+row)*256 + k0 + kq*8], &Bs[(size_t)(w*128 + it*64)*8]);
        }
        __syncthreads();
        bf16x8 af[4], bfr[4];
        #pragma unroll
        for (int mi=0; mi<4; ++mi) af[mi]  = *(bf16x8*)&As[aoff + mi*512];
        #pragma unroll
        for (int ni=0; ni<4; ++ni) bfr[ni] = *(bf16x8*)&Bs[boff + ni*512];
        #pragma unroll
        for (int mi=0; mi<4; ++mi)
            #pragma unroll
            for (int ni=0; ni<4; ++ni)
                acc[mi][ni] = __builtin_amdgcn_mfma_f32_16x16x32_bf16(af[mi], bfr[ni], acc[mi][ni], 0,0,0);
        __syncthreads();
    }

    int bufi = col0 >> 8;   // uniform per block
    u16* obuf = (bufi==0)?qb:((bufi==1)?kr0b:((bufi==2)?kr1b:((bufi==3)?vr0b:vr1b)));
    int cbase = col0 & 255;
    float bvv[4];
    #pragma unroll
    for (int ni=0; ni<4; ++ni) bvv[ni] = biasp[col0 + wn*64 + ni*16 + lm];

    int rowl_s = tid >> 3;              // 0..31
    int col8   = tid & 7;               // 0..7 (8 lcols each)
    int gcb    = (col8 >> 2)*64 + (col8 & 3)*8;

    #pragma unroll
    for (int p=0; p<2; ++p){
        if (p) __syncthreads();
        #pragma unroll
        for (int nj=0; nj<2; ++nj){
            int ni = p*2 + nj;
            int lcol = wn*32 + nj*16 + lm;
            #pragma unroll
            for (int mi=0; mi<4; ++mi){
                #pragma unroll
                for (int t=0; t<4; ++t){
                    int lr = wm*64 + mi*16 + quad*4 + t;
                    Cs[lr*66 + lcol] = acc[mi][ni][t] + bvv[ni];
                }
            }
        }
        __syncthreads();
        int cw = cbase + gcb + p*32;
        #pragma unroll
        for (int it=0; it<4; ++it){
            int rl = rowl_s + it*32;
            int r = row0 + rl;
            if (r < NN){
                const float* src = &Cs[rl*66 + col8*8];
                float4 c0 = *(const float4*)&src[0];
                float4 c1 = *(const float4*)&src[4];
                uint4 o;
                o.x = (unsigned)f2bf(c0.x) | ((unsigned)f2bf(c0.y)<<16);
                o.y = (unsigned)f2bf(c0.z) | ((unsigned)f2bf(c0.w)<<16);
                o.z = (unsigned)f2bf(c1.x) | ((unsigned)f2bf(c1.y)<<16);
                o.w = (unsigned)f2bf(c1.z) | ((unsigned)f2bf(c1.w)<<16);
                *(uint4*)&obuf[(size_t)r*256 + cw] = o;
            }
        }
    }
}

// ======================= K2: split-wave CSR attention, online softmax ==============
__global__ __launch_bounds__(256) void attn_k(const u16* __restrict__ qb,
        const u16* __restrict__ kr0b, const u16* __restrict__ kr1b,
        const u16* __restrict__ vr0b, const u16* __restrict__ vr1b,
        const int* __restrict__ row_ptr, const int* __restrict__ epk,
        const float* __restrict__ prel_l, u16* __restrict__ A2){
    int wv = threadIdx.x >> 6, lane = threadIdx.x & 63;
    int node = blockIdx.x*4 + wv;
    int l32 = lane & 31;
    int half = lane >> 5;
    int start = row_ptr[node], end = row_ptr[node+1];
    float qf[8];
    {
        uint4 qr = *(const uint4*)&qb[(size_t)node*256 + l32*8];
        dec8(qr, qf);
    }
    int h = l32 >> 2;
    float pr0 = prel_l[h]     * 0.17677669529663687f;   // /sqrt(32)
    float pr1 = prel_l[8 + h] * 0.17677669529663687f;
    float m = -INFINITY, s = 0.f;
    float acc[8] = {0.f,0.f,0.f,0.f,0.f,0.f,0.f,0.f};

    uint4 kraw = {0,0,0,0}, vraw = {0,0,0,0};
    float pscale = 0.f;
    int i0 = start + half;
    if (i0 < end){
        unsigned p = (unsigned)epk[i0];
        int src = p & 0x3FFFFFFF; unsigned rel = p >> 30;
        const u16* kb = rel ? kr1b : kr0b;
        const u16* vb = rel ? vr1b : vr0b;
        kraw = *(const uint4*)&kb[(size_t)src*256 + l32*8];
        vraw = *(const uint4*)&vb[(size_t)src*256 + l32*8];
        pscale = rel ? pr1 : pr0;
    }
    for (int i = i0; i < end; i += 2){
        uint4 kc = kraw, vc = vraw;
        float psc = pscale;
        if (i + 2 < end){
            unsigned p = (unsigned)epk[i+2];
            int src = p & 0x3FFFFFFF; unsigned rel = p >> 30;
            const u16* kb = rel ? kr1b : kr0b;
            const u16* vb = rel ? vr1b : vr0b;
            kraw = *(const uint4*)&kb[(size_t)src*256 + l32*8];
            vraw = *(const uint4*)&vb[(size_t)src*256 + l32*8];
            pscale = rel ? pr1 : pr0;
        }
        float kv[8];
        dec8(kc, kv);
        float p = qf[0]*kv[0]+qf[1]*kv[1]+qf[2]*kv[2]+qf[3]*kv[3]
                 +qf[4]*kv[4]+qf[5]*kv[5]+qf[6]*kv[6]+qf[7]*kv[7];
        p += __shfl_xor(p, 1);
        p += __shfl_xor(p, 2);
        float logit = p * psc;
        float mo = m;
        m = fmaxf(m, logit);
        float sc = __expf(mo - m);
        float pe = __expf(logit - m);
        s = s*sc + pe;
        float vv[8];
        dec8(vc, vv);
        #pragma unroll
        for (int j=0;j<8;++j) acc[j] = acc[j]*sc + pe*vv[j];
    }
    float mO = __shfl_xor(m, 32);
    float mA = fmaxf(m, mO);
    if (mA == -INFINITY) mA = 0.f;
    float eS = __expf(m - mA);
    float sh = s * eS;
    float sA = sh + __shfl_xor(sh, 32);
    float rs = 1.f / fmaxf(sA, 1e-16f);
    float oA[8];
    #pragma unroll
    for (int j=0;j<8;++j){
        float a = acc[j] * eS;
        oA[j] = a + __shfl_xor(a, 32);
    }
    if (half == 0){
        u16 o[8];
        #pragma unroll
        for (int j=0;j<8;++j) o[j] = f2bf(gelu_exact(oA[j]*rs));
        uint4 ov;
        ov.x = (unsigned)o[0] | ((unsigned)o[1]<<16);
        ov.y = (unsigned)o[2] | ((unsigned)o[3]<<16);
        ov.z = (unsigned)o[4] | ((unsigned)o[5]<<16);
        ov.w = (unsigned)o[6] | ((unsigned)o[7]<<16);
        *(uint4*)&A2[(size_t)node*256 + l32*8] = ov;
    }
}

// ======================= K3a: out GEMM + skip + relu + LN (layers 0-2) ===========
__global__ __launch_bounds__(256) void gemmOln_k(const u16* __restrict__ A,
        const u16* __restrict__ Wt, const float* __restrict__ bias,
        const float* __restrict__ h_in, const float* __restrict__ skip_l,
        const float* __restrict__ g, const float* __restrict__ b,
        float* __restrict__ h_out){
    __shared__ u16 As[2048];          // 64 rows x 32 k
    __shared__ u16 Bs[8192];          // 256 cols x 32 k
    __shared__ float part_s[64*33];
    __shared__ float part_q[64*33];
    __shared__ float mu_s[64], rstd_s[64];
    int tid = threadIdx.x;
    int w = tid >> 6, lane = tid & 63;
    int row0 = blockIdx.x * 64;
    int wm = w & 1, wn = w >> 1;
    f32x4 acc[2][8];
    #pragma unroll
    for (int i=0;i<2;++i)
        #pragma unroll
        for (int j=0;j<8;++j) acc[i][j] = (f32x4){0.f,0.f,0.f,0.f};

    int lm = lane & 15, quad = lane >> 4;
    int kq0 = quad ^ (lm & 3);
    int aoff = (wm*32 + lm)*32 + kq0*8;
    int boff = (wn*128 + lm)*32 + kq0*8;

    for (int k0 = 0; k0 < 256; k0 += 32){
        {
            int s = tid;
            int row = s >> 2, q0 = s & 3;
            int kq = q0 ^ (row & 3);
            gload_lds16(&A[(size_t)(row0+row)*256 + k0 + kq*8], &As[(size_t)(w*64)*8]);
        }
        #pragma unroll
        for (int it = 0; it < 4; ++it){
            int s = it*256 + w*64 + lane;
            int row = s >> 2, q0 = s & 3;
            int kq = q0 ^ (row & 3);
            gload_lds16(&Wt[(size_t)row*256 + k0 + kq*8], &Bs[(size_t)(it*256 + w*64)*8]);
        }
        __syncthreads();
        bf16x8 af[2], bfr[8];
        #pragma unroll
        for (int mi=0; mi<2; ++mi) af[mi]  = *(bf16x8*)&As[aoff + mi*512];
        #pragma unroll
        for (int ni=0; ni<8; ++ni) bfr[ni] = *(bf16x8*)&Bs[boff + ni*512];
        #pragma unroll
        for (int mi=0; mi<2; ++mi)
            #pragma unroll
            for (int ni=0; ni<8; ++ni)
                acc[mi][ni] = __builtin_amdgcn_mfma_f32_16x16x32_bf16(af[mi], bfr[ni], acc[mi][ni], 0,0,0);
        __syncthreads();
    }

    float sskip = 1.f/(1.f+__expf(-skip_l[0]));
    float osk = 1.f - sskip;
    float bv[8], gv[8], bbv[8];
    #pragma unroll
    for (int ni=0; ni<8; ++ni){
        int colg = wn*128 + ni*16 + lm;
        bv[ni]  = bias[colg];
        gv[ni]  = g[colg];
        bbv[ni] = b[colg];
    }
    #pragma unroll
    for (int mi=0; mi<2; ++mi){
        #pragma unroll
        for (int t=0; t<4; ++t){
            int lr = wm*32 + mi*16 + quad*4 + t;
            int r = row0 + lr;
            float ps = 0.f, pq = 0.f;
            #pragma unroll
            for (int ni=0; ni<8; ++ni){
                int colg = wn*128 + ni*16 + lm;
                float hv = (r < NN) ? h_in[(size_t)r*256 + colg] : 0.f;
                float val = sskip*(acc[mi][ni][t] + bv[ni]) + osk*hv;
                val = fmaxf(val, 0.f);
                acc[mi][ni][t] = val;
                ps += val; pq += val*val;
            }
            part_s[lr*33 + wn*16 + lm] = ps;
            part_q[lr*33 + wn*16 + lm] = pq;
        }
    }
    __syncthreads();
    if (tid < 64){
        float S = 0.f, Q = 0.f;
        #pragma unroll 8
        for (int t2=0; t2<32; ++t2){
            S += part_s[tid*33 + t2];
            Q += part_q[tid*33 + t2];
        }
        float mu = S * (1.f/256.f);
        float var = Q * (1.f/256.f) - mu*mu;
        mu_s[tid] = mu;
        rstd_s[tid] = rsqrtf(var + 1e-5f);
    }
    __syncthreads();
    #pragma unroll
    for (int mi=0; mi<2; ++mi){
        #pragma unroll
        for (int t=0; t<4; ++t){
            int lr = wm*32 + mi*16 + quad*4 + t;
            int r = row0 + lr;
            if (r >= NN) continue;
            float mu = mu_s[lr], rstd = rstd_s[lr];
            #pragma unroll
            for (int ni=0; ni<8; ++ni){
                int colg = wn*128 + ni*16 + lm;
                float o = (acc[mi][ni][t] - mu)*rstd*gv[ni] + bbv[ni];
                h_out[(size_t)r*256 + colg] = o;
            }
        }
    }
}

// ======================= K3b: out GEMM + skip blend (final layer) =======================
__global__ __launch_bounds__(256) void gemmO_k(const u16* __restrict__ A,
        const u16* __restrict__ Wt, const float* __restrict__ bias,
        const float* __restrict__ h_in, const float* __restrict__ skip_l,
        float* __restrict__ outp){
    __shared__ u16 As[4096];
    __shared__ u16 Bs[4096];
    int tid = threadIdx.x;
    int w = tid >> 6, lane = tid & 63;
    int row0 = blockIdx.x * 128;
    int col0 = blockIdx.y * 128;
    int wm = w & 1, wn = w >> 1;
    f32x4 acc[4][4];
    #pragma unroll
    for (int i=0;i<4;++i)
        #pragma unroll
        for (int j=0;j<4;++j) acc[i][j] = (f32x4){0.f,0.f,0.f,0.f};

    int lm = lane & 15, quad = lane >> 4;
    int kq0 = quad ^ (lm & 3);
    int aoff = (wm*64 + lm)*32 + kq0*8;
    int boff = (wn*64 + lm)*32 + kq0*8;

    for (int k0 = 0; k0 < 256; k0 += 32){
        #pragma unroll
        for (int it = 0; it < 2; ++it){
            int s = w*128 + it*64 + lane;
            int row = s >> 2, q0 = s & 3;
            int kq = q0 ^ (row & 3);
            gload_lds16(&A [(size_t)(row0+row)*256 + k0 + kq*8], &As[(size_t)(w*128 + it*64)*8]);
            gload_lds16(&Wt[(size_t)(col0+row)*256 + k0 + kq*8], &Bs[(size_t)(w*128 + it*64)*8]);
        }
        __syncthreads();
        bf16x8 af[4], bfr[4];
        #pragma unroll
        for (int mi=0; mi<4; ++mi) af[mi]  = *(bf16x8*)&As[aoff + mi*512];
        #pragma unroll
        for (int ni=0; ni<4; ++ni) bfr[ni] = *(bf16x8*)&Bs[boff + ni*512];
        #pragma unroll
        for (int mi=0; mi<4; ++mi)
            #pragma unroll
            for (int ni=0; ni<4; ++ni)
                acc[mi][ni] = __builtin_amdgcn_mfma_f32_16x16x32_bf16(af[mi], bfr[ni], acc[mi][ni], 0,0,0);
        __syncthreads();
    }
    float s = 1.f/(1.f+expf(-skip_l[0]));
    float os = 1.f - s;
    #pragma unroll
    for (int ni=0; ni<4; ++ni){
        int colg = col0 + wn*64 + ni*16 + lm;
        float bv = bias[colg];
        #pragma unroll
        for (int mi=0; mi<4; ++mi){
            #pragma unroll
            for (int t=0; t<4; ++t){
                int r = row0 + wm*64 + mi*16 + quad*4 + t;
                if (r < NN)
                    outp[(size_t)r*256 + colg] =
                        s*(acc[mi][ni][t] + bv) + os*h_in[(size_t)r*256 + colg];
            }
        }
    }
}

// ======================= host =======================
extern "C" void kernel_launch(void* const* d_in, const int* in_sizes, int n_in,
                              void* d_out, int out_size, void* d_ws, size_t ws_size,
                              hipStream_t stream){
    (void)in_sizes; (void)n_in; (void)out_size; (void)ws_size;
    const float* x     = (const float*)d_in[0];
    const int*   ei0   = (const int*)d_in[1];
    const int*   ei1   = (const int*)d_in[2];
    const float* kqv_w = (const float*)d_in[3];
    const float* kqv_b = (const float*)d_in[4];
    const float* out_w = (const float*)d_in[5];
    const float* out_b = (const float*)d_in[6];
    const float* skip  = (const float*)d_in[7];
    const float* krel  = (const float*)d_in[8];
    const float* vrel  = (const float*)d_in[9];
    const float* prel  = (const float*)d_in[10];
    const float* ln_g  = (const float*)d_in[11];
    const float* ln_b  = (const float*)d_in[12];
    float* outp = (float*)d_out;

    char* wp = (char*)d_ws;
    auto alloc = [&](size_t bytes)->void*{
        void* p = wp; wp += (bytes + 255) & ~(size_t)255; return p;
    };
    float* hA    = (float*)alloc((size_t)NN*CC*4);
    float* hB    = (float*)alloc((size_t)NN*CC*4);
    u16*   xbf   = (u16*)alloc((size_t)NPAD*CC*2);
    u16*   hbf   = (u16*)alloc((size_t)NPAD*CC*2);
    u16*   A2    = (u16*)alloc((size_t)NPAD*CC*2);
    u16*   qb    = (u16*)alloc((size_t)NN*CC*2);
    u16*   kr0b  = (u16*)alloc((size_t)NN*CC*2);
    u16*   kr1b  = (u16*)alloc((size_t)NN*CC*2);
    u16*   vr0b  = (u16*)alloc((size_t)NN*CC*2);
    u16*   vr1b  = (u16*)alloc((size_t)NN*CC*2);
    u16*   Wt5   = (u16*)alloc((size_t)4*1280*256*2);
    u16*   Wto   = (u16*)alloc((size_t)4*256*256*2);
    float* bias5 = (float*)alloc((size_t)4*1280*4);
    int* cnt     = (int*)alloc((size_t)NN*4);      // cnt+cursor adjacent: one memset
    int* cursor  = (int*)alloc((size_t)NN*4);
    int* incl    = (int*)alloc((size_t)NN*4);
    int* row_ptr = (int*)alloc((size_t)(NN+1)*4);
    int* bsum    = (int*)alloc(128*4);
    int* epk     = (int*)alloc((size_t)TE*4);

    // prep (weights + input cast) — independent of CSR chain
    build_w5_k<<<5120,256,0,stream>>>(kqv_w, krel, vrel, Wt5);
    build_bias5_k<<<20,256,0,stream>>>(kqv_b, krel, vrel, bias5);
    build_wo_k<<<1024,256,0,stream>>>(out_w, Wto);
    cvt_x_k<<<2500,256,0,stream>>>(x, xbf);

    // CSR build
    size_t cntBlk = ((size_t)NN*4 + 255) & ~(size_t)255;
    hipMemsetAsync(cnt, 0, cntBlk + (size_t)NN*4, stream);   // zero cnt AND cursor
    hist_k<<<1250,256,0,stream>>>(ei0, ei1, cnt);
    scan_block_k<<<79,256,0,stream>>>(cnt, incl, bsum);
    scan_bsum_k<<<1,128,0,stream>>>(bsum, 79);
    finalize_rowptr_k<<<79,256,0,stream>>>(cnt, incl, bsum, row_ptr);
    scatter_k<<<1250,256,0,stream>>>(ei0, ei1, row_ptr, cursor, epk);

    const float* h_in = x;
    const u16*   Ain  = xbf;
    float* houts[4] = {hA, hB, hA, outp};
    for (int l=0; l<4; ++l){
        gemm5_k<<<dim3(10,157),256,0,stream>>>(Ain, Wt5 + (size_t)l*327680,
                bias5 + l*1280, qb, kr0b, kr1b, vr0b, vr1b);
        attn_k<<<5000,256,0,stream>>>(qb, kr0b, kr1b, vr0b, vr1b,
                row_ptr, epk, prel + l*16, A2);
        if (l < 3){
            gemmOln_k<<<314,256,0,stream>>>(A2, Wto + (size_t)l*65536,
                    out_b + l*256, h_in, skip + l, ln_g + l*256, ln_b + l*256,
                    houts[l]);
            cvt_x_k<<<2500,256,0,stream>>>(houts[l], hbf);
        } else {
            gemmO_k<<<dim3(157,2),256,0,stream>>>(A2, Wto + (size_t)l*65536,
                    out_b + l*256, h_in, skip + l, outp);
        }
        h_in = houts[l];
        Ain = hbf;
    }
}